// Round 1
// baseline (1963.958 us; speedup 1.0000x reference)
//
#include <hip/hip_runtime.h>
#include <math.h>

#define T_ 243
#define P_ 17
#define L_ 4
#define C_ 128
#define H_ 8
#define NPTS_ 4
#define DH_ 16
#define B_ 2
#define LQ (T_*P_*L_)      /* 16524 */
#define NT1 (B_*LQ)        /* 33048 */
#define LL (L_+1)          /* 5 */
#define S_ (P_*LL)         /* 85 */
#define NT2 (B_*T_*P_*LL)  /* 41310 */

// ---------------- LN1 + q = xn + pe + learn_pos ----------------
__global__ void k_ln1_q(const float* __restrict__ x, const float* __restrict__ pe,
                        const float* __restrict__ lpos, const float* __restrict__ g1,
                        const float* __restrict__ be1, float* __restrict__ xn,
                        float* __restrict__ q) {
  int i = blockIdx.x;            // token in [0,NT1)
  int c = threadIdx.x;           // 128
  int b = i / LQ; int r = i % LQ;
  int t = r / (P_*L_); int rp = r % (P_*L_);
  int p = rp / L_; int lv = rp % L_;
  const float* xrow = x + (((size_t)(b*T_+t)*P_ + p)*LL + 1 + lv)*C_;
  float v = xrow[c];
  __shared__ float s1[128], s2[128];
  s1[c]=v; s2[c]=v*v; __syncthreads();
  for (int off=64; off>0; off>>=1){ if(c<off){s1[c]+=s1[c+off]; s2[c]+=s2[c+off];} __syncthreads(); }
  float mean = s1[0]*(1.0f/C_);
  float var  = s2[0]*(1.0f/C_) - mean*mean;
  float inv = rsqrtf(var + 1e-5f);
  float xnv = (v - mean)*inv*g1[c] + be1[c];
  size_t oi = (size_t)i*C_ + c;
  xn[oi] = xnv;
  size_t pidx = (((size_t)t*P_ + p)*L_ + lv)*C_ + c;
  q[oi] = xnv + pe[pidx] + lpos[pidx];
}

// ---------------- generic LN ----------------
__global__ void k_ln(const float* __restrict__ in, const float* __restrict__ g,
                     const float* __restrict__ be, float* __restrict__ out){
  int i = blockIdx.x; int c = threadIdx.x;
  float v = in[(size_t)i*C_ + c];
  __shared__ float s1[128], s2[128];
  s1[c]=v; s2[c]=v*v; __syncthreads();
  for (int off=64; off>0; off>>=1){ if(c<off){s1[c]+=s1[c+off]; s2[c]+=s2[c+off];} __syncthreads(); }
  float mean = s1[0]*(1.0f/C_);
  float var  = s2[0]*(1.0f/C_) - mean*mean;
  float inv = rsqrtf(var + 1e-5f);
  out[(size_t)i*C_ + c] = (v - mean)*inv*g[c] + be[c];
}

// ---------------- weight transpose: dst[c*rows+r] = src[r*cols+c] ----------------
__global__ void k_transpose(const float* __restrict__ src, float* __restrict__ dst,
                            int rows, int cols){
  int idx = blockIdx.x*blockDim.x + threadIdx.x;
  if (idx < rows*cols){ int r = idx/cols, cc = idx%cols; dst[(size_t)cc*rows + r] = src[idx]; }
}

// ---------------- per-token GEMM: out[i,j] = dot(in[i,:K], wt[:,j]) + b[j] ----------------
// wt layout: wt[k*N + j].  ACT==1 -> exact GELU.  RES==1 -> += res[i*N+j].
template<int K, int N, int ACT, int RES>
__global__ void k_gemm_tok(const float* __restrict__ in, const float* __restrict__ wt,
                           const float* __restrict__ bias, const float* __restrict__ res,
                           float* __restrict__ out){
  int i = blockIdx.x; int j = threadIdx.x; // N threads
  __shared__ float row[K];
  for (int k=j; k<K; k+=N) row[k] = in[(size_t)i*K + k];
  __syncthreads();
  float acc = bias[j];
  #pragma unroll 8
  for (int k=0; k<K; ++k) acc = fmaf(row[k], wt[(size_t)k*N + j], acc);
  if (ACT==1) acc = 0.5f*acc*(1.0f + erff(acc*0.70710678118654752440f));
  if (RES)    acc += res[(size_t)i*N + j];
  out[(size_t)i*N + j] = acc;
}

// ---------------- val GEMM with scatter into sampling layout ----------------
// vmap[lv][b][h][t][p][dh]
__global__ void k_val(const float* __restrict__ xn, const float* __restrict__ wt,
                      const float* __restrict__ bias, float* __restrict__ vmap){
  int i = blockIdx.x; int j = threadIdx.x; // 128
  __shared__ float row[128];
  row[j] = xn[(size_t)i*128 + j];
  __syncthreads();
  float acc = bias[j];
  #pragma unroll 8
  for (int k=0;k<128;++k) acc = fmaf(row[k], wt[k*128 + j], acc);
  int b = i / LQ; int r = i % LQ;
  int t = r/(P_*L_); int rp = r%(P_*L_); int p = rp/L_; int lv = rp%L_;
  int h = j / DH_; int dh = j % DH_;
  size_t vi = (((((size_t)lv*B_ + b)*H_ + h)*T_ + t)*P_ + p)*DH_ + dh;
  vmap[vi] = acc;
}

// ---------------- softmax over 16 points per (token, head), in place ----------------
__global__ void k_softmax_aw(float* __restrict__ aw){
  int i = blockIdx.x; int tid = threadIdx.x; // 128: head = tid/16, elem = tid%16
  size_t idx = (size_t)i*128 + tid;
  float v = aw[idx];
  float m = v;
  for (int d=1; d<16; d<<=1) m = fmaxf(m, __shfl_xor(m, d, 16));
  float e = __expf(v - m);
  float s = e;
  for (int d=1; d<16; d<<=1) s += __shfl_xor(s, d, 16);
  aw[idx] = e / s;
}

// ---------------- deformable sampling ----------------
// thread per (token, head, dh4): 16 samples, float4 channel chunks
__global__ void k_sample(const float* __restrict__ off, const float* __restrict__ aw,
                         const float* __restrict__ refp, const float* __restrict__ vmap,
                         float* __restrict__ o){
  int gid = blockIdx.x*blockDim.x + threadIdx.x;
  if (gid >= NT1*H_*(DH_/4)) return;
  int dh4 = gid & 3; int rest = gid >> 2;
  int h = rest & 7; int i = rest >> 3;   // token
  int b = i / LQ; int r = i % LQ;
  int t = r/(P_*L_); int rp = r%(P_*L_); int p = rp/L_;
  size_t rpi = (((size_t)b*T_+t)*P_+p)*2;
  float refx = refp[rpi + 0];
  float refy = refp[rpi + 1];
  float4 acc = make_float4(0.f,0.f,0.f,0.f);
  const float* offrow = off + ((size_t)i*H_ + h)*(L_*NPTS_*2);
  const float* awrow  = aw  + ((size_t)i*H_ + h)*(L_*NPTS_);
  #pragma unroll
  for (int lv=0; lv<L_; ++lv){
    const float* vbase = vmap + ((((size_t)lv*B_ + b)*H_ + h)*(size_t)(T_*P_))*DH_ + dh4*4;
    #pragma unroll
    for (int pt=0; pt<NPTS_; ++pt){
      float o0 = offrow[(lv*NPTS_+pt)*2+0];
      float o1 = offrow[(lv*NPTS_+pt)*2+1];
      float w  = awrow[lv*NPTS_+pt];
      // (ref + off/norm)*norm - 0.5 == ref*norm + off - 0.5
      float px = refx*P_ + o0 - 0.5f;
      float py = refy*T_ + o1 - 0.5f;
      float fx = floorf(px), fy = floorf(py);
      int x0 = (int)fx, y0 = (int)fy;
      float wx1 = px - fx, wx0 = 1.f - wx1;
      float wy1 = py - fy, wy0 = 1.f - wy1;
      float cw[4] = {w*wy0*wx0, w*wy0*wx1, w*wy1*wx0, w*wy1*wx1};
      int ys[4] = {y0, y0, y0+1, y0+1};
      int xs[4] = {x0, x0+1, x0, x0+1};
      #pragma unroll
      for (int cidx=0; cidx<4; ++cidx){
        int yy = ys[cidx], xx = xs[cidx];
        if (yy>=0 && yy<T_ && xx>=0 && xx<P_){
          const float4 v4 = *reinterpret_cast<const float4*>(vbase + ((size_t)yy*P_ + xx)*DH_);
          float wgt = cw[cidx];
          acc.x = fmaf(wgt, v4.x, acc.x);
          acc.y = fmaf(wgt, v4.y, acc.y);
          acc.z = fmaf(wgt, v4.z, acc.z);
          acc.w = fmaf(wgt, v4.w, acc.w);
        }
      }
    }
  }
  *reinterpret_cast<float4*>(o + (size_t)i*C_ + h*DH_ + dh4*4) = acc;
}

// ---------------- out-proj 1 (+residual from x) scattered into xcat ----------------
__global__ void k_outproj1(const float* __restrict__ o, const float* __restrict__ wt,
                           const float* __restrict__ bias, const float* __restrict__ x,
                           float* __restrict__ xcat){
  int i = blockIdx.x; int j = threadIdx.x; // 128
  __shared__ float row[128];
  row[j] = o[(size_t)i*128 + j];
  __syncthreads();
  float acc = bias[j];
  #pragma unroll 8
  for (int k=0;k<128;++k) acc = fmaf(row[k], wt[k*128 + j], acc);
  int b = i / LQ; int r = i % LQ;
  int t = r/(P_*L_); int rp = r%(P_*L_); int p = rp/L_; int lv = rp%L_;
  size_t xi = ((((size_t)(b*T_+t)*P_ + p)*LL) + 1 + lv)*C_ + j;
  xcat[xi] = acc + x[xi];
}

// ---------------- copy level-0 tokens ----------------
__global__ void k_copy_x0(const float* __restrict__ x, float* __restrict__ xcat){
  size_t idx = (size_t)blockIdx.x*blockDim.x + threadIdx.x;
  const size_t n = (size_t)B_*T_*P_*C_;
  if (idx < n){
    size_t c = idx % C_; size_t btp = idx / C_;
    size_t xi = (btp*LL)*C_ + c;
    xcat[xi] = x[xi];
  }
}

// ---------------- self-attention per (bt, head): S=85, DH=16 ----------------
__global__ void k_attn(const float* __restrict__ qkv, float* __restrict__ ca){
  int blk = blockIdx.x; // bt*H + h
  int h = blk % H_; int bt = blk / H_;
  int tid = threadIdx.x; // 128
  __shared__ float qs[S_][DH_+1], ks[S_][DH_+1], vs[S_][DH_+1];
  for (int idx = tid; idx < S_*DH_; idx += 128){
    int s = idx / DH_; int d = idx % DH_;
    const float* base = qkv + ((size_t)bt*S_ + s)*384 + h*DH_ + d;
    qs[s][d] = base[0]; ks[s][d] = base[128]; vs[s][d] = base[256];
  }
  __syncthreads();
  if (tid < S_){
    float sc[S_];
    float m = -1e30f;
    #pragma unroll 5
    for (int k=0;k<S_;++k){
      float a=0.f;
      #pragma unroll
      for (int d=0; d<DH_; ++d) a = fmaf(qs[tid][d], ks[k][d], a);
      a *= 0.25f;
      sc[k]=a; m = fmaxf(m,a);
    }
    float sum=0.f;
    #pragma unroll 5
    for (int k=0;k<S_;++k){ float e=__expf(sc[k]-m); sc[k]=e; sum+=e; }
    float inv = 1.f/sum;
    float* crow = ca + ((size_t)bt*S_ + tid)*C_ + h*DH_;
    #pragma unroll
    for (int d=0; d<DH_; ++d){
      float a=0.f;
      #pragma unroll 5
      for (int k=0;k<S_;++k) a = fmaf(sc[k], vs[k][d], a);
      crow[d] = a*inv;
    }
  }
}

extern "C" void kernel_launch(void* const* d_in, const int* in_sizes, int n_in,
                              void* d_out, int out_size, void* d_ws, size_t ws_size,
                              hipStream_t stream) {
  (void)in_sizes; (void)n_in; (void)out_size;
  const float* x      = (const float*)d_in[0];
  const float* refp   = (const float*)d_in[1];
  const float* pe     = (const float*)d_in[2];
  const float* lpos   = (const float*)d_in[3];
  const float* w_off  = (const float*)d_in[4];
  const float* b_off  = (const float*)d_in[5];
  const float* w_attn = (const float*)d_in[6];
  const float* b_attn = (const float*)d_in[7];
  const float* w_val  = (const float*)d_in[8];
  const float* b_val  = (const float*)d_in[9];
  const float* w_out  = (const float*)d_in[10];
  const float* b_out  = (const float*)d_in[11];
  const float* in_w   = (const float*)d_in[12];
  const float* in_b   = (const float*)d_in[13];
  const float* out_w  = (const float*)d_in[14];
  const float* out_b  = (const float*)d_in[15];
  const float* fc1_w  = (const float*)d_in[16];
  const float* fc1_b  = (const float*)d_in[17];
  const float* fc2_w  = (const float*)d_in[18];
  const float* fc2_b  = (const float*)d_in[19];
  const float* g1     = (const float*)d_in[20];
  const float* be1    = (const float*)d_in[21];
  const float* g2     = (const float*)d_in[22];
  const float* be2    = (const float*)d_in[23];
  const float* g3     = (const float*)d_in[24];
  const float* be3    = (const float*)d_in[25];
  float* out = (float*)d_out;
  float* ws = (float*)d_ws;
  (void)ws_size;

  // ---- workspace layout (floats) ----
  size_t off_xn   = 0;                                // NT1*128
  size_t off_q    = off_xn  + (size_t)NT1*128;        // NT1*128
  size_t off_off  = off_q   + (size_t)NT1*128;        // NT1*256
  size_t off_aw   = off_off + (size_t)NT1*256;        // NT1*128
  size_t off_vm   = off_aw  + (size_t)NT1*128;        // NT1*128
  size_t off_o    = off_vm  + (size_t)NT1*128;        // NT1*128
  size_t off_xcat = off_o   + (size_t)NT1*128;        // NT2*128
  size_t off_xn2  = off_xcat+ (size_t)NT2*128;        // NT2*128
  size_t off_qkv  = off_xn2 + (size_t)NT2*128;        // NT2*384
  size_t off_wT   = off_qkv + (size_t)NT2*384;        // transposed weights
  // reuse (dead regions):
  size_t off_ca   = off_xn;    // NT2*128 <= xn+q region
  size_t off_hid  = off_off;   // NT2*512 == off+aw+vm+o region exactly
  size_t off_ln3  = off_xn2;   // xn2 dead after qkv

  float* xnB   = ws + off_xn;
  float* qB    = ws + off_q;
  float* offB  = ws + off_off;
  float* awB   = ws + off_aw;
  float* vmB   = ws + off_vm;
  float* oB    = ws + off_o;
  float* xcatB = ws + off_xcat;
  float* xn2B  = ws + off_xn2;
  float* qkvB  = ws + off_qkv;
  float* caB   = ws + off_ca;
  float* hidB  = ws + off_hid;
  float* ln3B  = ws + off_ln3;

  // transposed weights
  float* w_off_t  = ws + off_wT;                 // 128*256
  float* w_attn_t = w_off_t  + 128*256;          // 128*128
  float* w_val_t  = w_attn_t + 128*128;
  float* w_out_t  = w_val_t  + 128*128;
  float* in_w_t   = w_out_t  + 128*128;          // 128*384
  float* out_w_t  = in_w_t   + 128*384;          // 128*128
  float* fc1_t    = out_w_t  + 128*128;          // 128*512
  float* fc2_t    = fc1_t    + 128*512;          // 512*128

  auto tr = [&](const float* src, float* dst, int rows, int cols){
    int n = rows*cols;
    hipLaunchKernelGGL(k_transpose, dim3((n+255)/256), dim3(256), 0, stream, src, dst, rows, cols);
  };
  tr(w_off, w_off_t, 256, 128);
  tr(w_attn, w_attn_t, 128, 128);
  tr(w_val, w_val_t, 128, 128);
  tr(w_out, w_out_t, 128, 128);
  tr(in_w, in_w_t, 384, 128);
  tr(out_w, out_w_t, 128, 128);
  tr(fc1_w, fc1_t, 512, 128);
  tr(fc2_w, fc2_t, 128, 512);

  // 1. LN1 + q
  hipLaunchKernelGGL(k_ln1_q, dim3(NT1), dim3(128), 0, stream, x, pe, lpos, g1, be1, xnB, qB);
  // 2. off / attn-logits / val
  hipLaunchKernelGGL((k_gemm_tok<128,256,0,0>), dim3(NT1), dim3(256), 0, stream, qB, w_off_t, b_off, nullptr, offB);
  hipLaunchKernelGGL((k_gemm_tok<128,128,0,0>), dim3(NT1), dim3(128), 0, stream, qB, w_attn_t, b_attn, nullptr, awB);
  hipLaunchKernelGGL(k_val, dim3(NT1), dim3(128), 0, stream, xnB, w_val_t, b_val, vmB);
  // 3. softmax over sampling weights
  hipLaunchKernelGGL(k_softmax_aw, dim3(NT1), dim3(128), 0, stream, awB);
  // 4. deformable bilinear sampling
  hipLaunchKernelGGL(k_sample, dim3((NT1*H_*(DH_/4)+255)/256), dim3(256), 0, stream, offB, awB, refp, vmB, oB);
  // 5. out-proj1 + residual -> xcat (levels 1..4), copy level 0
  hipLaunchKernelGGL(k_outproj1, dim3(NT1), dim3(128), 0, stream, oB, w_out_t, b_out, x, xcatB);
  hipLaunchKernelGGL(k_copy_x0, dim3(((size_t)B_*T_*P_*C_+255)/256), dim3(256), 0, stream, x, xcatB);
  // 6. LN2
  hipLaunchKernelGGL(k_ln, dim3(NT2), dim3(128), 0, stream, xcatB, g2, be2, xn2B);
  // 7. qkv
  hipLaunchKernelGGL((k_gemm_tok<128,384,0,0>), dim3(NT2), dim3(384), 0, stream, xn2B, in_w_t, in_b, nullptr, qkvB);
  // 8. attention
  hipLaunchKernelGGL(k_attn, dim3(B_*T_*H_), dim3(128), 0, stream, qkvB, caB);
  // 9. out-proj2 + residual (in-place on xcat)
  hipLaunchKernelGGL((k_gemm_tok<128,128,0,1>), dim3(NT2), dim3(128), 0, stream, caB, out_w_t, out_b, xcatB, xcatB);
  // 10. LN3 + FFN + residual
  hipLaunchKernelGGL(k_ln, dim3(NT2), dim3(128), 0, stream, xcatB, g3, be3, ln3B);
  hipLaunchKernelGGL((k_gemm_tok<128,512,1,0>), dim3(NT2), dim3(512), 0, stream, ln3B, fc1_t, fc1_b, nullptr, hidB);
  hipLaunchKernelGGL((k_gemm_tok<512,128,0,1>), dim3(NT2), dim3(128), 0, stream, hidB, fc2_t, fc2_b, xcatB, out);
}

// Round 2
// 422.510 us; speedup vs baseline: 4.6483x; 4.6483x over previous
//
#include <hip/hip_runtime.h>
#include <math.h>

#define T_ 243
#define P_ 17
#define L_ 4
#define C_ 128
#define H_ 8
#define NPTS_ 4
#define DH_ 16
#define B_ 2
#define LQ (T_*P_*L_)      /* 16524 */
#define NT1 (B_*LQ)        /* 33048 */
#define LL (L_+1)          /* 5 */
#define S_ (P_*LL)         /* 85 */
#define NT2 (B_*T_*P_*LL)  /* 41310 */

typedef __attribute__((ext_vector_type(8))) short short8v;
typedef __attribute__((ext_vector_type(4))) float float4v;

__device__ __forceinline__ unsigned short f2bf(float f){
  union { float f; unsigned u; } un; un.f = f;
  unsigned r = un.u + 0x7FFF + ((un.u >> 16) & 1);   // RNE
  return (unsigned short)(r >> 16);
}

// ---------------- weight convert fp32 -> bf16, layout preserved [N][K] ----------------
__global__ void k_wcvt(const float* __restrict__ w0, const float* __restrict__ w1,
                       const float* __restrict__ w2, const float* __restrict__ w3,
                       const float* __restrict__ w4, const float* __restrict__ w5,
                       const float* __restrict__ w6, const float* __restrict__ w7,
                       unsigned short* __restrict__ dst){
  int i = blockIdx.x*256 + threadIdx.x;
  if (i >= 278528) return;
  float v;
  if      (i < 32768)  v = w0[i];
  else if (i < 49152)  v = w1[i-32768];
  else if (i < 65536)  v = w2[i-49152];
  else if (i < 81920)  v = w3[i-65536];
  else if (i < 131072) v = w4[i-81920];
  else if (i < 147456) v = w5[i-131072];
  else if (i < 212992) v = w6[i-147456];
  else                 v = w7[i-212992];
  dst[i] = f2bf(v);
}

// ---------------- LN1 + q = xn + pe + learn_pos (bf16 outputs) ----------------
__global__ void k_ln1_q(const float* __restrict__ x, const float* __restrict__ pe,
                        const float* __restrict__ lpos, const float* __restrict__ g1,
                        const float* __restrict__ be1, unsigned short* __restrict__ xn,
                        unsigned short* __restrict__ q) {
  int i = blockIdx.x;            // token in [0,NT1)
  int c = threadIdx.x;           // 128
  int b = i / LQ; int r = i % LQ;
  int t = r / (P_*L_); int rp = r % (P_*L_);
  int p = rp / L_; int lv = rp % L_;
  const float* xrow = x + (((size_t)(b*T_+t)*P_ + p)*LL + 1 + lv)*C_;
  float v = xrow[c];
  __shared__ float s1[128], s2[128];
  s1[c]=v; s2[c]=v*v; __syncthreads();
  for (int off=64; off>0; off>>=1){ if(c<off){s1[c]+=s1[c+off]; s2[c]+=s2[c+off];} __syncthreads(); }
  float mean = s1[0]*(1.0f/C_);
  float var  = s2[0]*(1.0f/C_) - mean*mean;
  float inv = rsqrtf(var + 1e-5f);
  float xnv = (v - mean)*inv*g1[c] + be1[c];
  size_t oi = (size_t)i*C_ + c;
  xn[oi] = f2bf(xnv);
  size_t pidx = (((size_t)t*P_ + p)*L_ + lv)*C_ + c;
  q[oi] = f2bf(xnv + pe[pidx] + lpos[pidx]);
}

// ---------------- generic LN (bf16 output) ----------------
__global__ void k_ln(const float* __restrict__ in, const float* __restrict__ g,
                     const float* __restrict__ be, unsigned short* __restrict__ out){
  int i = blockIdx.x; int c = threadIdx.x;
  float v = in[(size_t)i*C_ + c];
  __shared__ float s1[128], s2[128];
  s1[c]=v; s2[c]=v*v; __syncthreads();
  for (int off=64; off>0; off>>=1){ if(c<off){s1[c]+=s1[c+off]; s2[c]+=s2[c+off];} __syncthreads(); }
  float mean = s1[0]*(1.0f/C_);
  float var  = s2[0]*(1.0f/C_) - mean*mean;
  float inv = rsqrtf(var + 1e-5f);
  out[(size_t)i*C_ + c] = f2bf((v - mean)*inv*g[c] + be[c]);
}

// ---------------- tiled bf16 MFMA GEMM ----------------
// A: [M][K] bf16, Bw: [N][K] bf16 (original weight layout!), per-block tile 128x128.
// LDS layout: chunk-transposed [c][row] where c = k/8 (16-byte chunks), row 0..127.
// EPI: 0 plain fp32  1 VAL-scatter  2 OUT1-scatter+res(x)  3 RES (+res[i*N+j])  4 FC1 (GELU->bf16)
template<int K, int N, int EPI>
__global__ __launch_bounds__(256) void k_mm(
    const unsigned short* __restrict__ A, const unsigned short* __restrict__ Bw,
    const float* __restrict__ bias, const float* __restrict__ res,
    float* __restrict__ outF, unsigned short* __restrict__ outB,
    const float* __restrict__ xres, int M)
{
  constexpr int NSTAGE = K / 128;
  __shared__ unsigned short As[16*128*8];  // ushort index (c*128+row)*8
  __shared__ unsigned short Bs[16*128*8];
  int tid = threadIdx.x;
  int m0 = blockIdx.x * 128;
  int n0 = blockIdx.y * 128;
  int lane = tid & 63;
  int w = tid >> 6;
  int wm = (w >> 1) * 64, wn = (w & 1) * 64;
  int lr = lane & 15;
  int kg = lane >> 4;
  float4v acc[4][4] = {};
  for (int st = 0; st < NSTAGE; ++st) {
    int kk = st * 128;
    #pragma unroll
    for (int s = 0; s < 8; ++s) {
      int c  = (tid & 3) + (s & 3) * 4;
      int row = (tid >> 2) + (s >> 2) * 64;
      int gr = m0 + row;
      short8v v = {};
      if (gr < M) v = *(const short8v*)(A + (size_t)gr * K + kk + c * 8);
      *(short8v*)(As + (c * 128 + row) * 8) = v;
    }
    #pragma unroll
    for (int s = 0; s < 8; ++s) {
      int c  = (tid & 3) + (s & 3) * 4;
      int row = (tid >> 2) + (s >> 2) * 64;
      short8v v = *(const short8v*)(Bw + (size_t)(n0 + row) * K + kk + c * 8);
      *(short8v*)(Bs + (c * 128 + row) * 8) = v;
    }
    __syncthreads();
    #pragma unroll
    for (int ks = 0; ks < 4; ++ks) {
      short8v af[4], bf[4];
      #pragma unroll
      for (int mf = 0; mf < 4; ++mf)
        af[mf] = *(const short8v*)(As + (((ks*4 + kg) * 128) + wm + mf*16 + lr) * 8);
      #pragma unroll
      for (int nf = 0; nf < 4; ++nf)
        bf[nf] = *(const short8v*)(Bs + (((ks*4 + kg) * 128) + wn + nf*16 + lr) * 8);
      #pragma unroll
      for (int mf = 0; mf < 4; ++mf)
        #pragma unroll
        for (int nf = 0; nf < 4; ++nf)
          acc[mf][nf] = __builtin_amdgcn_mfma_f32_16x16x32_bf16(af[mf], bf[nf], acc[mf][nf], 0, 0, 0);
    }
    __syncthreads();
  }
  // epilogue: D row = m0+wm+mf*16 + kg*4 + j, col = n0+wn+nf*16 + lr  (m89-verified)
  #pragma unroll
  for (int mf = 0; mf < 4; ++mf) {
    #pragma unroll
    for (int j = 0; j < 4; ++j) {
      int gr = m0 + wm + mf*16 + kg*4 + j;
      if (gr >= M) continue;
      int b=0,t=0,p=0,lv=0;
      if (EPI == 1 || EPI == 2) {
        b = gr / LQ; int r = gr % LQ;
        t = r / (P_*L_); int rp = r % (P_*L_);
        p = rp / L_; lv = rp % L_;
      }
      #pragma unroll
      for (int nf = 0; nf < 4; ++nf) {
        int gc = n0 + wn + nf*16 + lr;
        float v = acc[mf][nf][j] + bias[gc];
        if (EPI == 0) {
          outF[(size_t)gr*N + gc] = v;
        } else if (EPI == 1) {       // val scatter: vmap[lv][b][h][t][p][dh]
          int h = gc >> 4; int dh = gc & 15;
          size_t vi = (((((size_t)lv*B_ + b)*H_ + h)*T_ + t)*P_ + p)*DH_ + dh;
          outF[vi] = v;
        } else if (EPI == 2) {       // out1 scatter into xcat + residual x
          size_t xi = ((((size_t)(b*T_+t)*P_ + p)*LL) + 1 + lv)*(size_t)C_ + gc;
          outF[xi] = v + xres[xi];
        } else if (EPI == 3) {       // += res
          outF[(size_t)gr*N + gc] = v + res[(size_t)gr*N + gc];
        } else if (EPI == 4) {       // GELU -> bf16
          float gv = 0.5f*v*(1.0f + erff(v*0.70710678118654752440f));
          outB[(size_t)gr*N + gc] = f2bf(gv);
        }
      }
    }
  }
}

// ---------------- softmax over 16 points per (token, head), in place ----------------
__global__ void k_softmax_aw(float* __restrict__ aw){
  int i = blockIdx.x; int tid = threadIdx.x; // 128: head = tid/16, elem = tid%16
  size_t idx = (size_t)i*128 + tid;
  float v = aw[idx];
  float m = v;
  for (int d=1; d<16; d<<=1) m = fmaxf(m, __shfl_xor(m, d, 16));
  float e = __expf(v - m);
  float s = e;
  for (int d=1; d<16; d<<=1) s += __shfl_xor(s, d, 16);
  aw[idx] = e / s;
}

// ---------------- deformable sampling (bf16 output) ----------------
__global__ void k_sample(const float* __restrict__ off, const float* __restrict__ aw,
                         const float* __restrict__ refp, const float* __restrict__ vmap,
                         unsigned short* __restrict__ o){
  int gid = blockIdx.x*blockDim.x + threadIdx.x;
  if (gid >= NT1*H_*(DH_/4)) return;
  int dh4 = gid & 3; int rest = gid >> 2;
  int h = rest & 7; int i = rest >> 3;   // token
  int b = i / LQ; int r = i % LQ;
  int t = r/(P_*L_); int rp = r%(P_*L_); int p = rp/L_;
  size_t rpi = (((size_t)b*T_+t)*P_+p)*2;
  float refx = refp[rpi + 0];
  float refy = refp[rpi + 1];
  float4 acc = make_float4(0.f,0.f,0.f,0.f);
  const float* offrow = off + ((size_t)i*H_ + h)*(L_*NPTS_*2);
  const float* awrow  = aw  + ((size_t)i*H_ + h)*(L_*NPTS_);
  #pragma unroll
  for (int lv=0; lv<L_; ++lv){
    const float* vbase = vmap + ((((size_t)lv*B_ + b)*H_ + h)*(size_t)(T_*P_))*DH_ + dh4*4;
    #pragma unroll
    for (int pt=0; pt<NPTS_; ++pt){
      float o0 = offrow[(lv*NPTS_+pt)*2+0];
      float o1 = offrow[(lv*NPTS_+pt)*2+1];
      float w  = awrow[lv*NPTS_+pt];
      float px = refx*P_ + o0 - 0.5f;
      float py = refy*T_ + o1 - 0.5f;
      float fx = floorf(px), fy = floorf(py);
      int x0 = (int)fx, y0 = (int)fy;
      float wx1 = px - fx, wx0 = 1.f - wx1;
      float wy1 = py - fy, wy0 = 1.f - wy1;
      float cw[4] = {w*wy0*wx0, w*wy0*wx1, w*wy1*wx0, w*wy1*wx1};
      int ys[4] = {y0, y0, y0+1, y0+1};
      int xs[4] = {x0, x0+1, x0, x0+1};
      #pragma unroll
      for (int cidx=0; cidx<4; ++cidx){
        int yy = ys[cidx], xx = xs[cidx];
        if (yy>=0 && yy<T_ && xx>=0 && xx<P_){
          const float4 v4 = *reinterpret_cast<const float4*>(vbase + ((size_t)yy*P_ + xx)*DH_);
          float wgt = cw[cidx];
          acc.x = fmaf(wgt, v4.x, acc.x);
          acc.y = fmaf(wgt, v4.y, acc.y);
          acc.z = fmaf(wgt, v4.z, acc.z);
          acc.w = fmaf(wgt, v4.w, acc.w);
        }
      }
    }
  }
  unsigned short* op = o + (size_t)i*C_ + h*DH_ + dh4*4;
  op[0] = f2bf(acc.x); op[1] = f2bf(acc.y); op[2] = f2bf(acc.z); op[3] = f2bf(acc.w);
}

// ---------------- copy level-0 tokens ----------------
__global__ void k_copy_x0(const float* __restrict__ x, float* __restrict__ xcat){
  size_t idx = (size_t)blockIdx.x*blockDim.x + threadIdx.x;
  const size_t n = (size_t)B_*T_*P_*C_;
  if (idx < n){
    size_t c = idx % C_; size_t btp = idx / C_;
    size_t xi = (btp*LL)*C_ + c;
    xcat[xi] = x[xi];
  }
}

// ---------------- flash self-attention per (bt, head): S=85, DH=16 ----------------
__global__ __launch_bounds__(128) void k_attn2(const float* __restrict__ qkv,
                                               unsigned short* __restrict__ ca){
  int blk = blockIdx.x; int h = blk & 7; int bt = blk >> 3;
  int tid = threadIdx.x;
  __shared__ float ks[S_][DH_], vs[S_][DH_];
  const float* base = qkv + (size_t)bt*S_*384 + h*DH_;
  for (int idx = tid; idx < S_*DH_; idx += 128){
    int s = idx >> 4, d = idx & 15;
    ks[s][d] = base[(size_t)s*384 + 128 + d];
    vs[s][d] = base[(size_t)s*384 + 256 + d];
  }
  __syncthreads();
  if (tid < S_){
    float q[16];
    #pragma unroll
    for (int d = 0; d < 16; ++d) q[d] = base[(size_t)tid*384 + d] * 0.25f;
    float o[16] = {0.f,0.f,0.f,0.f,0.f,0.f,0.f,0.f,0.f,0.f,0.f,0.f,0.f,0.f,0.f,0.f};
    float m = -1e30f, l = 0.f;
    for (int k = 0; k < S_; ++k){
      float s = 0.f;
      #pragma unroll
      for (int d = 0; d < 16; ++d) s = fmaf(q[d], ks[k][d], s);
      float mn = fmaxf(m, s);
      float sc = __expf(m - mn);
      float pv = __expf(s - mn);
      l = l*sc + pv;
      #pragma unroll
      for (int d = 0; d < 16; ++d) o[d] = o[d]*sc + pv*vs[k][d];
      m = mn;
    }
    float inv = 1.f/l;
    unsigned short* crow = ca + ((size_t)bt*S_ + tid)*C_ + h*DH_;
    #pragma unroll
    for (int d = 0; d < 16; ++d) crow[d] = f2bf(o[d]*inv);
  }
}

extern "C" void kernel_launch(void* const* d_in, const int* in_sizes, int n_in,
                              void* d_out, int out_size, void* d_ws, size_t ws_size,
                              hipStream_t stream) {
  (void)in_sizes; (void)n_in; (void)out_size; (void)ws_size;
  const float* x      = (const float*)d_in[0];
  const float* refp   = (const float*)d_in[1];
  const float* pe     = (const float*)d_in[2];
  const float* lpos   = (const float*)d_in[3];
  const float* w_off  = (const float*)d_in[4];
  const float* b_off  = (const float*)d_in[5];
  const float* w_attn = (const float*)d_in[6];
  const float* b_attn = (const float*)d_in[7];
  const float* w_val  = (const float*)d_in[8];
  const float* b_val  = (const float*)d_in[9];
  const float* w_out  = (const float*)d_in[10];
  const float* b_out  = (const float*)d_in[11];
  const float* in_w   = (const float*)d_in[12];
  const float* in_b   = (const float*)d_in[13];
  const float* out_w  = (const float*)d_in[14];
  const float* out_b  = (const float*)d_in[15];
  const float* fc1_w  = (const float*)d_in[16];
  const float* fc1_b  = (const float*)d_in[17];
  const float* fc2_w  = (const float*)d_in[18];
  const float* fc2_b  = (const float*)d_in[19];
  const float* g1     = (const float*)d_in[20];
  const float* be1    = (const float*)d_in[21];
  const float* g2     = (const float*)d_in[22];
  const float* be2    = (const float*)d_in[23];
  const float* g3     = (const float*)d_in[24];
  const float* be3    = (const float*)d_in[25];
  float* out = (float*)d_out;
  char* wsb = (char*)d_ws;

  // ---- workspace layout (byte offsets, 256-aligned) ----
  unsigned short* xn_b  = (unsigned short*)(wsb + 0);                    // NT1*128 bf16
  unsigned short* q_b   = (unsigned short*)(wsb + 8460288);              // NT1*128 bf16
  float*          offB  = (float*)(wsb + 16920576);                      // NT1*256 f32
  float*          awB   = (float*)(wsb + 50761728);                      // NT1*128 f32
  float*          vmB   = (float*)(wsb + 67682304);                      // NT1*128 f32
  unsigned short* o_b   = (unsigned short*)(wsb + 84602880);             // NT1*128 bf16
  float*          xcatB = (float*)(wsb + 93063168);                      // NT2*128 f32
  unsigned short* xn2_b = (unsigned short*)(wsb + 114213888);            // NT2*128 bf16
  float*          qkvB  = (float*)(wsb + 124789248);                     // NT2*384 f32
  unsigned short* wb    = (unsigned short*)(wsb + 188241408);            // 278528 bf16
  // reuse of dead regions:
  unsigned short* ca_b  = (unsigned short*)(wsb + 0);                    // NT2*128 bf16 (<= xn+q)
  unsigned short* ln3_b = (unsigned short*)(wsb + 114213888);            // NT2*128 bf16 (xn2 dead)
  unsigned short* hid_b = (unsigned short*)(wsb + 124789248);            // NT2*512 bf16 (qkv dead)

  unsigned short* wb_off  = wb + 0;
  unsigned short* wb_attn = wb + 32768;
  unsigned short* wb_val  = wb + 49152;
  unsigned short* wb_wout = wb + 65536;
  unsigned short* wb_in   = wb + 81920;
  unsigned short* wb_outw = wb + 131072;
  unsigned short* wb_fc1  = wb + 147456;
  unsigned short* wb_fc2  = wb + 212992;

  const int GM1 = (NT1 + 127)/128;  // 259
  const int GM2 = (NT2 + 127)/128;  // 323

  // 0. weights -> bf16
  hipLaunchKernelGGL(k_wcvt, dim3((278528+255)/256), dim3(256), 0, stream,
                     w_off, w_attn, w_val, w_out, in_w, out_w, fc1_w, fc2_w, wb);
  // 1. LN1 + q
  hipLaunchKernelGGL(k_ln1_q, dim3(NT1), dim3(128), 0, stream, x, pe, lpos, g1, be1, xn_b, q_b);
  // 2. off / attn-logits / val
  hipLaunchKernelGGL((k_mm<128,256,0>), dim3(GM1,2), dim3(256), 0, stream,
                     q_b, wb_off, b_off, nullptr, offB, nullptr, nullptr, NT1);
  hipLaunchKernelGGL((k_mm<128,128,0>), dim3(GM1,1), dim3(256), 0, stream,
                     q_b, wb_attn, b_attn, nullptr, awB, nullptr, nullptr, NT1);
  hipLaunchKernelGGL((k_mm<128,128,1>), dim3(GM1,1), dim3(256), 0, stream,
                     xn_b, wb_val, b_val, nullptr, vmB, nullptr, nullptr, NT1);
  // 3. softmax on sampling weights
  hipLaunchKernelGGL(k_softmax_aw, dim3(NT1), dim3(128), 0, stream, awB);
  // 4. deformable bilinear sampling
  hipLaunchKernelGGL(k_sample, dim3((NT1*H_*(DH_/4)+255)/256), dim3(256), 0, stream,
                     offB, awB, refp, vmB, o_b);
  // 5. out-proj1 + residual -> xcat (levels 1..4), copy level 0
  hipLaunchKernelGGL((k_mm<128,128,2>), dim3(GM1,1), dim3(256), 0, stream,
                     o_b, wb_wout, b_out, nullptr, xcatB, nullptr, x, NT1);
  hipLaunchKernelGGL(k_copy_x0, dim3(((size_t)B_*T_*P_*C_+255)/256), dim3(256), 0, stream, x, xcatB);
  // 6. LN2 -> bf16
  hipLaunchKernelGGL(k_ln, dim3(NT2), dim3(128), 0, stream, xcatB, g2, be2, xn2_b);
  // 7. qkv
  hipLaunchKernelGGL((k_mm<128,384,0>), dim3(GM2,3), dim3(256), 0, stream,
                     xn2_b, wb_in, in_b, nullptr, qkvB, nullptr, nullptr, NT2);
  // 8. flash attention
  hipLaunchKernelGGL(k_attn2, dim3(B_*T_*H_), dim3(128), 0, stream, qkvB, ca_b);
  // 9. out-proj2 + residual (in-place on xcat)
  hipLaunchKernelGGL((k_mm<128,128,3>), dim3(GM2,1), dim3(256), 0, stream,
                     ca_b, wb_outw, out_b, xcatB, xcatB, nullptr, nullptr, NT2);
  // 10. LN3 -> bf16, FFN, residual
  hipLaunchKernelGGL(k_ln, dim3(NT2), dim3(128), 0, stream, xcatB, g3, be3, ln3_b);
  hipLaunchKernelGGL((k_mm<128,512,4>), dim3(GM2,4), dim3(256), 0, stream,
                     ln3_b, wb_fc1, fc1_b, nullptr, nullptr, hid_b, nullptr, NT2);
  hipLaunchKernelGGL((k_mm<512,128,3>), dim3(GM2,1), dim3(256), 0, stream,
                     hid_b, wb_fc2, fc2_b, xcatB, out, nullptr, nullptr, NT2);
}

// Round 3
// 324.857 us; speedup vs baseline: 6.0456x; 1.3006x over previous
//
#include <hip/hip_runtime.h>
#include <math.h>

#define T_ 243
#define P_ 17
#define L_ 4
#define C_ 128
#define H_ 8
#define NPTS_ 4
#define DH_ 16
#define B_ 2
#define LQ (T_*P_*L_)      /* 16524 */
#define NT1 (B_*LQ)        /* 33048 */
#define LL (L_+1)          /* 5 */
#define S_ (P_*LL)         /* 85 */
#define NT2 (B_*T_*P_*LL)  /* 41310 */

typedef __attribute__((ext_vector_type(8))) short short8v;
typedef __attribute__((ext_vector_type(4))) float float4v;

__device__ __forceinline__ unsigned short f2bf(float f){
  union { float f; unsigned u; } un; un.f = f;
  unsigned r = un.u + 0x7FFF + ((un.u >> 16) & 1);   // RNE
  return (unsigned short)(r >> 16);
}
__device__ __forceinline__ float bf2f(unsigned short u){
  union { unsigned u; float f; } un; un.u = ((unsigned)u) << 16; return un.f;
}

// ---------------- weight convert fp32 -> bf16, layout preserved [N][K] ----------------
__global__ void k_wcvt(const float* __restrict__ w0, const float* __restrict__ w1,
                       const float* __restrict__ w2, const float* __restrict__ w3,
                       const float* __restrict__ w4, const float* __restrict__ w5,
                       const float* __restrict__ w6, const float* __restrict__ w7,
                       unsigned short* __restrict__ dst){
  int i = blockIdx.x*256 + threadIdx.x;
  if (i >= 278528) return;
  float v;
  if      (i < 32768)  v = w0[i];
  else if (i < 49152)  v = w1[i-32768];
  else if (i < 65536)  v = w2[i-49152];
  else if (i < 81920)  v = w3[i-65536];
  else if (i < 131072) v = w4[i-81920];
  else if (i < 147456) v = w5[i-131072];
  else if (i < 212992) v = w6[i-147456];
  else                 v = w7[i-212992];
  dst[i] = f2bf(v);
}

// ---------------- LN1 + q = xn + pe + learn_pos (bf16 outputs) ----------------
__global__ void k_ln1_q(const float* __restrict__ x, const float* __restrict__ pe,
                        const float* __restrict__ lpos, const float* __restrict__ g1,
                        const float* __restrict__ be1, unsigned short* __restrict__ xn,
                        unsigned short* __restrict__ q) {
  int i = blockIdx.x;            // token in [0,NT1)
  int c = threadIdx.x;           // 128
  int b = i / LQ; int r = i % LQ;
  int t = r / (P_*L_); int rp = r % (P_*L_);
  int p = rp / L_; int lv = rp % L_;
  const float* xrow = x + (((size_t)(b*T_+t)*P_ + p)*LL + 1 + lv)*C_;
  float v = xrow[c];
  __shared__ float s1[128], s2[128];
  s1[c]=v; s2[c]=v*v; __syncthreads();
  for (int off=64; off>0; off>>=1){ if(c<off){s1[c]+=s1[c+off]; s2[c]+=s2[c+off];} __syncthreads(); }
  float mean = s1[0]*(1.0f/C_);
  float var  = s2[0]*(1.0f/C_) - mean*mean;
  float inv = rsqrtf(var + 1e-5f);
  float xnv = (v - mean)*inv*g1[c] + be1[c];
  size_t oi = (size_t)i*C_ + c;
  xn[oi] = f2bf(xnv);
  size_t pidx = (((size_t)t*P_ + p)*L_ + lv)*C_ + c;
  q[oi] = f2bf(xnv + pe[pidx] + lpos[pidx]);
}

// ---------------- generic LN (bf16 output) ----------------
__global__ void k_ln(const float* __restrict__ in, const float* __restrict__ g,
                     const float* __restrict__ be, unsigned short* __restrict__ out){
  int i = blockIdx.x; int c = threadIdx.x;
  float v = in[(size_t)i*C_ + c];
  __shared__ float s1[128], s2[128];
  s1[c]=v; s2[c]=v*v; __syncthreads();
  for (int off=64; off>0; off>>=1){ if(c<off){s1[c]+=s1[c+off]; s2[c]+=s2[c+off];} __syncthreads(); }
  float mean = s1[0]*(1.0f/C_);
  float var  = s2[0]*(1.0f/C_) - mean*mean;
  float inv = rsqrtf(var + 1e-5f);
  out[(size_t)i*C_ + c] = f2bf((v - mean)*inv*g[c] + be[c]);
}

// ---------------- tiled bf16 MFMA GEMM ----------------
// A: [M][K] bf16, Bw: [N][K] bf16 (original weight layout), per-block tile 128x128.
// EPI: 0 fp32  2 OUT1-scatter+res(x)  3 fp32 +res  4 GELU->bf16  5 plain bf16
template<int K, int N, int EPI>
__global__ __launch_bounds__(256) void k_mm(
    const unsigned short* __restrict__ A, const unsigned short* __restrict__ Bw,
    const float* __restrict__ bias, const float* __restrict__ res,
    float* __restrict__ outF, unsigned short* __restrict__ outB,
    const float* __restrict__ xres, int M)
{
  constexpr int NSTAGE = K / 128;
  __shared__ unsigned short As[16*128*8];  // ushort index (c*128+row)*8
  __shared__ unsigned short Bs[16*128*8];
  int tid = threadIdx.x;
  int m0 = blockIdx.x * 128;
  int n0 = blockIdx.y * 128;
  int lane = tid & 63;
  int w = tid >> 6;
  int wm = (w >> 1) * 64, wn = (w & 1) * 64;
  int lr = lane & 15;
  int kg = lane >> 4;
  float4v acc[4][4] = {};
  for (int st = 0; st < NSTAGE; ++st) {
    int kk = st * 128;
    #pragma unroll
    for (int s = 0; s < 8; ++s) {
      int c  = (tid & 3) + (s & 3) * 4;
      int row = (tid >> 2) + (s >> 2) * 64;
      int gr = m0 + row;
      short8v v = {};
      if (gr < M) v = *(const short8v*)(A + (size_t)gr * K + kk + c * 8);
      *(short8v*)(As + (c * 128 + row) * 8) = v;
    }
    #pragma unroll
    for (int s = 0; s < 8; ++s) {
      int c  = (tid & 3) + (s & 3) * 4;
      int row = (tid >> 2) + (s >> 2) * 64;
      short8v v = *(const short8v*)(Bw + (size_t)(n0 + row) * K + kk + c * 8);
      *(short8v*)(Bs + (c * 128 + row) * 8) = v;
    }
    __syncthreads();
    #pragma unroll
    for (int ks = 0; ks < 4; ++ks) {
      short8v af[4], bfv[4];
      #pragma unroll
      for (int mf = 0; mf < 4; ++mf)
        af[mf] = *(const short8v*)(As + (((ks*4 + kg) * 128) + wm + mf*16 + lr) * 8);
      #pragma unroll
      for (int nf = 0; nf < 4; ++nf)
        bfv[nf] = *(const short8v*)(Bs + (((ks*4 + kg) * 128) + wn + nf*16 + lr) * 8);
      #pragma unroll
      for (int mf = 0; mf < 4; ++mf)
        #pragma unroll
        for (int nf = 0; nf < 4; ++nf)
          acc[mf][nf] = __builtin_amdgcn_mfma_f32_16x16x32_bf16(af[mf], bfv[nf], acc[mf][nf], 0, 0, 0);
    }
    __syncthreads();
  }
  // D row = m0+wm+mf*16 + kg*4 + j, col = n0+wn+nf*16 + lr
  #pragma unroll
  for (int mf = 0; mf < 4; ++mf) {
    #pragma unroll
    for (int j = 0; j < 4; ++j) {
      int gr = m0 + wm + mf*16 + kg*4 + j;
      if (gr >= M) continue;
      int b=0,t=0,p=0,lv=0;
      if (EPI == 2) {
        b = gr / LQ; int r = gr % LQ;
        t = r / (P_*L_); int rp = r % (P_*L_);
        p = rp / L_; lv = rp % L_;
      }
      #pragma unroll
      for (int nf = 0; nf < 4; ++nf) {
        int gc = n0 + wn + nf*16 + lr;
        float v = acc[mf][nf][j] + bias[gc];
        if (EPI == 0) {
          outF[(size_t)gr*N + gc] = v;
        } else if (EPI == 2) {       // out1 scatter into xcat + residual x
          size_t xi = ((((size_t)(b*T_+t)*P_ + p)*LL) + 1 + lv)*(size_t)C_ + gc;
          outF[xi] = v + xres[xi];
        } else if (EPI == 3) {       // += res, fp32 out
          outF[(size_t)gr*N + gc] = v + res[(size_t)gr*N + gc];
        } else if (EPI == 4) {       // GELU -> bf16
          float gv = 0.5f*v*(1.0f + erff(v*0.70710678118654752440f));
          outB[(size_t)gr*N + gc] = f2bf(gv);
        } else if (EPI == 5) {       // plain bf16
          outB[(size_t)gr*N + gc] = f2bf(v);
        }
      }
    }
  }
}

// ---------------- fused softmax + deformable sampling ----------------
// thread per (token, head): reads off(32 bf16) + aw-logits(16 bf16) once,
// in-register softmax, gathers vmap (bf16, plain [token][h*16+dh] layout).
__global__ __launch_bounds__(256) void k_sample(
    const unsigned short* __restrict__ off, const unsigned short* __restrict__ awl,
    const float* __restrict__ refp, const unsigned short* __restrict__ vmap,
    unsigned short* __restrict__ o){
  int gid = blockIdx.x*256 + threadIdx.x;
  if (gid >= NT1*H_) return;
  int h = gid & 7; int i = gid >> 3;
  int b = i / LQ; int r = i % LQ;
  int t = r/(P_*L_); int rp = r%(P_*L_); int p = rp/L_;
  size_t rpi = (((size_t)b*T_+t)*P_+p)*2;
  float refx = refp[rpi + 0]*P_ - 0.5f;
  float refy = refp[rpi + 1]*T_ - 0.5f;

  float offv[32];
  {
    const short8v* op8 = (const short8v*)(off + (size_t)i*256 + h*32);
    #pragma unroll
    for (int s=0;s<4;++s){ short8v v = op8[s];
      #pragma unroll
      for (int j=0;j<8;++j) offv[s*8+j] = bf2f((unsigned short)v[j]); }
  }
  float awv[16];
  {
    const short8v* ap8 = (const short8v*)(awl + (size_t)i*128 + h*16);
    #pragma unroll
    for (int s=0;s<2;++s){ short8v v = ap8[s];
      #pragma unroll
      for (int j=0;j<8;++j) awv[s*8+j] = bf2f((unsigned short)v[j]); }
  }
  // softmax over the 16 logits
  float m = awv[0];
  #pragma unroll
  for (int k=1;k<16;++k) m = fmaxf(m, awv[k]);
  float sum = 0.f;
  #pragma unroll
  for (int k=0;k<16;++k){ awv[k] = __expf(awv[k]-m); sum += awv[k]; }
  float inv = 1.f/sum;
  #pragma unroll
  for (int k=0;k<16;++k) awv[k] *= inv;

  float acc[16];
  #pragma unroll
  for (int d=0;d<16;++d) acc[d]=0.f;

  #pragma unroll
  for (int lv=0; lv<L_; ++lv){
    const unsigned short* vlv = vmap + ((size_t)b*LQ + lv)*128 + h*16;
    #pragma unroll
    for (int pt=0; pt<NPTS_; ++pt){
      float px = refx + offv[(lv*4+pt)*2+0];
      float py = refy + offv[(lv*4+pt)*2+1];
      float w  = awv[lv*4+pt];
      float fx = floorf(px), fy = floorf(py);
      int x0 = (int)fx, y0 = (int)fy;
      float wx1 = px - fx, wx0 = 1.f - wx1;
      float wy1 = py - fy, wy0 = 1.f - wy1;
      float cw[4] = {w*wy0*wx0, w*wy0*wx1, w*wy1*wx0, w*wy1*wx1};
      int ys[4] = {y0, y0, y0+1, y0+1};
      int xs[4] = {x0, x0+1, x0, x0+1};
      #pragma unroll
      for (int cidx=0; cidx<4; ++cidx){
        int yy = ys[cidx], xx = xs[cidx];
        if (yy>=0 && yy<T_ && xx>=0 && xx<P_){
          const short8v* vp = (const short8v*)(vlv + (size_t)(yy*P_ + xx)*(L_*128));
          short8v v0 = vp[0], v1 = vp[1];
          float wgt = cw[cidx];
          #pragma unroll
          for (int d=0;d<8;++d){
            acc[d]   = fmaf(wgt, bf2f((unsigned short)v0[d]), acc[d]);
            acc[8+d] = fmaf(wgt, bf2f((unsigned short)v1[d]), acc[8+d]);
          }
        }
      }
    }
  }
  short8v o0, o1;
  #pragma unroll
  for (int d=0;d<8;++d){ o0[d] = (short)f2bf(acc[d]); o1[d] = (short)f2bf(acc[8+d]); }
  short8v* op = (short8v*)(o + (size_t)i*C_ + h*DH_);
  op[0] = o0; op[1] = o1;
}

// ---------------- copy level-0 tokens ----------------
__global__ void k_copy_x0(const float* __restrict__ x, float* __restrict__ xcat){
  size_t idx = (size_t)blockIdx.x*blockDim.x + threadIdx.x;
  const size_t n = (size_t)B_*T_*P_*C_;
  if (idx < n){
    size_t c = idx % C_; size_t btp = idx / C_;
    size_t xi = (btp*LL)*C_ + c;
    xcat[xi] = x[xi];
  }
}

// ---------------- flash self-attention per (bt, head): S=85, DH=16, bf16 qkv ----------------
__global__ __launch_bounds__(128) void k_attn2(const unsigned short* __restrict__ qkv,
                                               unsigned short* __restrict__ ca){
  int blk = blockIdx.x; int h = blk & 7; int bt = blk >> 3;
  int tid = threadIdx.x;
  __shared__ float ks[S_][DH_], vs[S_][DH_];
  const unsigned short* base = qkv + (size_t)bt*S_*384 + h*DH_;
  for (int idx = tid; idx < S_*DH_; idx += 128){
    int s = idx >> 4, d = idx & 15;
    ks[s][d] = bf2f(base[(size_t)s*384 + 128 + d]);
    vs[s][d] = bf2f(base[(size_t)s*384 + 256 + d]);
  }
  __syncthreads();
  if (tid < S_){
    float q[16];
    #pragma unroll
    for (int d = 0; d < 16; ++d) q[d] = bf2f(base[(size_t)tid*384 + d]) * 0.25f;
    float o[16] = {0.f,0.f,0.f,0.f,0.f,0.f,0.f,0.f,0.f,0.f,0.f,0.f,0.f,0.f,0.f,0.f};
    float m = -1e30f, l = 0.f;
    for (int k = 0; k < S_; ++k){
      float s = 0.f;
      #pragma unroll
      for (int d = 0; d < 16; ++d) s = fmaf(q[d], ks[k][d], s);
      float mn = fmaxf(m, s);
      float sc = __expf(m - mn);
      float pv = __expf(s - mn);
      l = l*sc + pv;
      #pragma unroll
      for (int d = 0; d < 16; ++d) o[d] = o[d]*sc + pv*vs[k][d];
      m = mn;
    }
    float inv = 1.f/l;
    unsigned short* crow = ca + ((size_t)bt*S_ + tid)*C_ + h*DH_;
    #pragma unroll
    for (int d = 0; d < 16; ++d) crow[d] = f2bf(o[d]*inv);
  }
}

extern "C" void kernel_launch(void* const* d_in, const int* in_sizes, int n_in,
                              void* d_out, int out_size, void* d_ws, size_t ws_size,
                              hipStream_t stream) {
  (void)in_sizes; (void)n_in; (void)out_size; (void)ws_size;
  const float* x      = (const float*)d_in[0];
  const float* refp   = (const float*)d_in[1];
  const float* pe     = (const float*)d_in[2];
  const float* lpos   = (const float*)d_in[3];
  const float* w_off  = (const float*)d_in[4];
  const float* b_off  = (const float*)d_in[5];
  const float* w_attn = (const float*)d_in[6];
  const float* b_attn = (const float*)d_in[7];
  const float* w_val  = (const float*)d_in[8];
  const float* b_val  = (const float*)d_in[9];
  const float* w_out  = (const float*)d_in[10];
  const float* b_out  = (const float*)d_in[11];
  const float* in_w   = (const float*)d_in[12];
  const float* in_b   = (const float*)d_in[13];
  const float* out_w  = (const float*)d_in[14];
  const float* out_b  = (const float*)d_in[15];
  const float* fc1_w  = (const float*)d_in[16];
  const float* fc1_b  = (const float*)d_in[17];
  const float* fc2_w  = (const float*)d_in[18];
  const float* fc2_b  = (const float*)d_in[19];
  const float* g1     = (const float*)d_in[20];
  const float* be1    = (const float*)d_in[21];
  const float* g2     = (const float*)d_in[22];
  const float* be2    = (const float*)d_in[23];
  const float* g3     = (const float*)d_in[24];
  const float* be3    = (const float*)d_in[25];
  float* out = (float*)d_out;
  char* wsb = (char*)d_ws;

  // ---- workspace layout (byte offsets) ----
  unsigned short* xn_b  = (unsigned short*)(wsb + 0);            // NT1*128 bf16 (8,460,288 B)
  unsigned short* q_b   = (unsigned short*)(wsb + 8460288);      // NT1*128 bf16
  unsigned short* off_b = (unsigned short*)(wsb + 16920576);     // NT1*256 bf16 (16,920,576 B)
  unsigned short* aw_b  = (unsigned short*)(wsb + 33841152);     // NT1*128 bf16
  unsigned short* vm_b  = (unsigned short*)(wsb + 42301440);     // NT1*128 bf16
  unsigned short* o_b   = (unsigned short*)(wsb + 50761728);     // NT1*128 bf16
  float*          xcatB = (float*)(wsb + 59222016);              // NT2*128 f32 (21,150,720 B)
  unsigned short* xn2_b = (unsigned short*)(wsb + 80372736);     // NT2*128 bf16 (10,575,360 B)
  unsigned short* qkv_b = (unsigned short*)(wsb + 90948096);     // NT2*384 bf16 (31,726,080 B)
  unsigned short* wb    = (unsigned short*)(wsb + 122674176);    // 278528 bf16
  // reuse of dead regions:
  unsigned short* ca_b  = (unsigned short*)(wsb + 0);            // NT2*128 bf16 (xn+q dead)
  unsigned short* ln3_b = (unsigned short*)(wsb + 80372736);     // xn2 dead
  unsigned short* hid_b = (unsigned short*)(wsb + 16920576);     // NT2*512 bf16 (off..o dead, 42,301,440 B exact)

  unsigned short* wb_off  = wb + 0;
  unsigned short* wb_attn = wb + 32768;
  unsigned short* wb_val  = wb + 49152;
  unsigned short* wb_wout = wb + 65536;
  unsigned short* wb_in   = wb + 81920;
  unsigned short* wb_outw = wb + 131072;
  unsigned short* wb_fc1  = wb + 147456;
  unsigned short* wb_fc2  = wb + 212992;

  const int GM1 = (NT1 + 127)/128;  // 259
  const int GM2 = (NT2 + 127)/128;  // 323

  // 0. weights -> bf16
  hipLaunchKernelGGL(k_wcvt, dim3((278528+255)/256), dim3(256), 0, stream,
                     w_off, w_attn, w_val, w_out, in_w, out_w, fc1_w, fc2_w, wb);
  // 1. LN1 + q
  hipLaunchKernelGGL(k_ln1_q, dim3(NT1), dim3(128), 0, stream, x, pe, lpos, g1, be1, xn_b, q_b);
  // 2. off / attn-logits / val  (all bf16 plain outputs)
  hipLaunchKernelGGL((k_mm<128,256,5>), dim3(GM1,2), dim3(256), 0, stream,
                     q_b, wb_off, b_off, nullptr, nullptr, off_b, nullptr, NT1);
  hipLaunchKernelGGL((k_mm<128,128,5>), dim3(GM1,1), dim3(256), 0, stream,
                     q_b, wb_attn, b_attn, nullptr, nullptr, aw_b, nullptr, NT1);
  hipLaunchKernelGGL((k_mm<128,128,5>), dim3(GM1,1), dim3(256), 0, stream,
                     xn_b, wb_val, b_val, nullptr, nullptr, vm_b, nullptr, NT1);
  // 3. fused softmax + deformable sampling
  hipLaunchKernelGGL(k_sample, dim3((NT1*H_+255)/256), dim3(256), 0, stream,
                     off_b, aw_b, refp, vm_b, o_b);
  // 4. out-proj1 + residual -> xcat (levels 1..4), copy level 0
  hipLaunchKernelGGL((k_mm<128,128,2>), dim3(GM1,1), dim3(256), 0, stream,
                     o_b, wb_wout, b_out, nullptr, xcatB, nullptr, x, NT1);
  hipLaunchKernelGGL(k_copy_x0, dim3(((size_t)B_*T_*P_*C_+255)/256), dim3(256), 0, stream, x, xcatB);
  // 5. LN2 -> bf16
  hipLaunchKernelGGL(k_ln, dim3(NT2), dim3(128), 0, stream, xcatB, g2, be2, xn2_b);
  // 6. qkv (bf16)
  hipLaunchKernelGGL((k_mm<128,384,5>), dim3(GM2,3), dim3(256), 0, stream,
                     xn2_b, wb_in, in_b, nullptr, nullptr, qkv_b, nullptr, NT2);
  // 7. flash attention
  hipLaunchKernelGGL(k_attn2, dim3(B_*T_*H_), dim3(128), 0, stream, qkv_b, ca_b);
  // 8. out-proj2 + residual (in-place on xcat)
  hipLaunchKernelGGL((k_mm<128,128,3>), dim3(GM2,1), dim3(256), 0, stream,
                     ca_b, wb_outw, out_b, xcatB, xcatB, nullptr, nullptr, NT2);
  // 9. LN3 -> bf16, FFN, residual
  hipLaunchKernelGGL(k_ln, dim3(NT2), dim3(128), 0, stream, xcatB, g3, be3, ln3_b);
  hipLaunchKernelGGL((k_mm<128,512,4>), dim3(GM2,4), dim3(256), 0, stream,
                     ln3_b, wb_fc1, fc1_b, nullptr, nullptr, hid_b, nullptr, NT2);
  hipLaunchKernelGGL((k_mm<512,128,3>), dim3(GM2,1), dim3(256), 0, stream,
                     hid_b, wb_fc2, fc2_b, xcatB, out, nullptr, nullptr, NT2);
}

// Round 6
// 266.168 us; speedup vs baseline: 7.3786x; 1.2205x over previous
//
#include <hip/hip_runtime.h>
#include <math.h>

#define T_ 243
#define P_ 17
#define L_ 4
#define C_ 128
#define H_ 8
#define NPTS_ 4
#define DH_ 16
#define B_ 2
#define LQ (T_*P_*L_)      /* 16524 */
#define NT1 (B_*LQ)        /* 33048 */
#define LL (L_+1)          /* 5 */
#define S_ (P_*LL)         /* 85 */
#define NT2 (B_*T_*P_*LL)  /* 41310 */

typedef __attribute__((ext_vector_type(8))) short short8v;
typedef __attribute__((ext_vector_type(4))) short short4v;
typedef __attribute__((ext_vector_type(4))) float float4v;

__device__ __forceinline__ unsigned short f2bf(float f){
  union { float f; unsigned u; } un; un.f = f;
  unsigned r = un.u + 0x7FFF + ((un.u >> 16) & 1);   // RNE
  return (unsigned short)(r >> 16);
}
__device__ __forceinline__ float bf2f(unsigned short u){
  union { unsigned u; float f; } un; un.u = ((unsigned)u) << 16; return un.f;
}

// ---------------- weight convert fp32 -> bf16, layout preserved [N][K] ----------------
__global__ void k_wcvt(const float* __restrict__ w0, const float* __restrict__ w1,
                       const float* __restrict__ w2, const float* __restrict__ w3,
                       const float* __restrict__ w4, const float* __restrict__ w5,
                       const float* __restrict__ w6, const float* __restrict__ w7,
                       unsigned short* __restrict__ dst){
  int i = blockIdx.x*256 + threadIdx.x;
  if (i >= 278528) return;
  float v;
  if      (i < 32768)  v = w0[i];
  else if (i < 49152)  v = w1[i-32768];
  else if (i < 65536)  v = w2[i-49152];
  else if (i < 81920)  v = w3[i-65536];
  else if (i < 131072) v = w4[i-81920];
  else if (i < 147456) v = w5[i-131072];
  else if (i < 212992) v = w6[i-147456];
  else                 v = w7[i-212992];
  dst[i] = f2bf(v);
}

// ---------------- LN1 + q = xn + pe + learn_pos (wave per row) ----------------
__global__ __launch_bounds__(256) void k_ln1_q(
    const float* __restrict__ x, const float* __restrict__ pe,
    const float* __restrict__ lpos, const float* __restrict__ g1,
    const float* __restrict__ be1, unsigned short* __restrict__ xn,
    unsigned short* __restrict__ q) {
  int w = threadIdx.x >> 6; int lane = threadIdx.x & 63;
  int i = blockIdx.x*4 + w;            // NT1 % 4 == 0
  int c = lane*2;
  int b = i / LQ; int r = i % LQ;
  int t = r / (P_*L_); int rp = r % (P_*L_);
  int p = rp / L_; int lv = rp % L_;
  const float* xrow = x + (((size_t)(b*T_+t)*P_ + p)*LL + 1 + lv)*C_;
  float2 v = *(const float2*)(xrow + c);
  float s1 = v.x + v.y, s2 = v.x*v.x + v.y*v.y;
  #pragma unroll
  for (int d=1; d<64; d<<=1){ s1 += __shfl_xor(s1,d); s2 += __shfl_xor(s2,d); }
  float mean = s1*(1.0f/C_);
  float var  = s2*(1.0f/C_) - mean*mean;
  float inv = rsqrtf(var + 1e-5f);
  float2 gg = *(const float2*)(g1 + c);
  float2 bb = *(const float2*)(be1 + c);
  float xn0 = (v.x - mean)*inv*gg.x + bb.x;
  float xn1 = (v.y - mean)*inv*gg.y + bb.y;
  size_t oi = (size_t)i*C_ + c;
  *(unsigned*)(xn + oi) = (unsigned)f2bf(xn0) | ((unsigned)f2bf(xn1) << 16);
  size_t pidx = (((size_t)t*P_ + p)*L_ + lv)*C_ + c;
  float2 pv = *(const float2*)(pe + pidx);
  float2 lp = *(const float2*)(lpos + pidx);
  *(unsigned*)(q + oi) = (unsigned)f2bf(xn0 + pv.x + lp.x) | ((unsigned)f2bf(xn1 + pv.y + lp.y) << 16);
}

// ---------------- generic LN (wave per row, bf16 out) ----------------
__global__ __launch_bounds__(256) void k_ln(
    const float* __restrict__ in, const float* __restrict__ g,
    const float* __restrict__ be, unsigned short* __restrict__ out, int M){
  int w = threadIdx.x >> 6; int lane = threadIdx.x & 63;
  int i = blockIdx.x*4 + w;
  if (i >= M) return;
  int c = lane*2;
  float2 v = *(const float2*)(in + (size_t)i*C_ + c);
  float s1 = v.x + v.y, s2 = v.x*v.x + v.y*v.y;
  #pragma unroll
  for (int d=1; d<64; d<<=1){ s1 += __shfl_xor(s1,d); s2 += __shfl_xor(s2,d); }
  float mean = s1*(1.0f/C_);
  float var  = s2*(1.0f/C_) - mean*mean;
  float inv = rsqrtf(var + 1e-5f);
  float2 gg = *(const float2*)(g + c);
  float2 bb = *(const float2*)(be + c);
  float o0 = (v.x - mean)*inv*gg.x + bb.x;
  float o1 = (v.y - mean)*inv*gg.y + bb.y;
  *(unsigned*)(out + (size_t)i*C_ + c) = (unsigned)f2bf(o0) | ((unsigned)f2bf(o1) << 16);
}

// ---------------- tiled bf16 MFMA GEMM ----------------
// A: [M][K] bf16, Bw: [N][K] bf16 (original weight layout), per-block tile 128x128.
// EPI: 0 fp32  2 OUT1-scatter+res(x)  3 fp32 +res  4 GELU->bf16  5 plain bf16
template<int K, int N, int EPI>
__global__ __launch_bounds__(256) void k_mm(
    const unsigned short* __restrict__ A, const unsigned short* __restrict__ Bw,
    const float* __restrict__ bias, const float* __restrict__ res,
    float* __restrict__ outF, unsigned short* __restrict__ outB,
    const float* __restrict__ xres, int M)
{
  constexpr int NSTAGE = K / 128;
  __shared__ unsigned short As[16*128*8];  // ushort index (c*128+row)*8
  __shared__ unsigned short Bs[16*128*8];
  int tid = threadIdx.x;
  int m0 = blockIdx.x * 128;
  int n0 = blockIdx.y * 128;
  int lane = tid & 63;
  int w = tid >> 6;
  int wm = (w >> 1) * 64, wn = (w & 1) * 64;
  int lr = lane & 15;
  int kg = lane >> 4;
  float4v acc[4][4] = {};
  for (int st = 0; st < NSTAGE; ++st) {
    int kk = st * 128;
    #pragma unroll
    for (int s = 0; s < 8; ++s) {
      int c  = (tid & 3) + (s & 3) * 4;
      int row = (tid >> 2) + (s >> 2) * 64;
      int gr = m0 + row;
      short8v v = {};
      if (gr < M) v = *(const short8v*)(A + (size_t)gr * K + kk + c * 8);
      *(short8v*)(As + (c * 128 + row) * 8) = v;
    }
    #pragma unroll
    for (int s = 0; s < 8; ++s) {
      int c  = (tid & 3) + (s & 3) * 4;
      int row = (tid >> 2) + (s >> 2) * 64;
      short8v v = *(const short8v*)(Bw + (size_t)(n0 + row) * K + kk + c * 8);
      *(short8v*)(Bs + (c * 128 + row) * 8) = v;
    }
    __syncthreads();
    #pragma unroll
    for (int ks = 0; ks < 4; ++ks) {
      short8v af[4], bfv[4];
      #pragma unroll
      for (int mf = 0; mf < 4; ++mf)
        af[mf] = *(const short8v*)(As + (((ks*4 + kg) * 128) + wm + mf*16 + lr) * 8);
      #pragma unroll
      for (int nf = 0; nf < 4; ++nf)
        bfv[nf] = *(const short8v*)(Bs + (((ks*4 + kg) * 128) + wn + nf*16 + lr) * 8);
      #pragma unroll
      for (int mf = 0; mf < 4; ++mf)
        #pragma unroll
        for (int nf = 0; nf < 4; ++nf)
          acc[mf][nf] = __builtin_amdgcn_mfma_f32_16x16x32_bf16(af[mf], bfv[nf], acc[mf][nf], 0, 0, 0);
    }
    __syncthreads();
  }
  // D row = m0+wm+mf*16 + kg*4 + j, col = n0+wn+nf*16 + lr
  #pragma unroll
  for (int mf = 0; mf < 4; ++mf) {
    #pragma unroll
    for (int j = 0; j < 4; ++j) {
      int gr = m0 + wm + mf*16 + kg*4 + j;
      if (gr >= M) continue;
      int b=0,t=0,p=0,lv=0;
      if (EPI == 2) {
        b = gr / LQ; int r = gr % LQ;
        t = r / (P_*L_); int rp = r % (P_*L_);
        p = rp / L_; lv = rp % L_;
      }
      #pragma unroll
      for (int nf = 0; nf < 4; ++nf) {
        int gc = n0 + wn + nf*16 + lr;
        float v = acc[mf][nf][j] + bias[gc];
        if (EPI == 0) {
          outF[(size_t)gr*N + gc] = v;
        } else if (EPI == 2) {       // out1 scatter into xcat + residual x
          size_t xi = ((((size_t)(b*T_+t)*P_ + p)*LL) + 1 + lv)*(size_t)C_ + gc;
          outF[xi] = v + xres[xi];
        } else if (EPI == 3) {       // += res, fp32 out
          outF[(size_t)gr*N + gc] = v + res[(size_t)gr*N + gc];
        } else if (EPI == 4) {       // GELU -> bf16
          float gv = 0.5f*v*(1.0f + erff(v*0.70710678118654752440f));
          outB[(size_t)gr*N + gc] = f2bf(gv);
        } else if (EPI == 5) {       // plain bf16
          outB[(size_t)gr*N + gc] = f2bf(v);
        }
      }
    }
  }
}

// ---------------- fused softmax + deformable sampling ----------------
__global__ __launch_bounds__(256) void k_sample(
    const unsigned short* __restrict__ off, const unsigned short* __restrict__ awl,
    const float* __restrict__ refp, const unsigned short* __restrict__ vmap,
    unsigned short* __restrict__ o){
  int gid = blockIdx.x*256 + threadIdx.x;
  if (gid >= NT1*H_) return;
  int h = gid & 7; int i = gid >> 3;
  int b = i / LQ; int r = i % LQ;
  int t = r/(P_*L_); int rp = r%(P_*L_); int p = rp/L_;
  size_t rpi = (((size_t)b*T_+t)*P_+p)*2;
  float refx = refp[rpi + 0]*P_ - 0.5f;
  float refy = refp[rpi + 1]*T_ - 0.5f;

  float offv[32];
  {
    const short8v* op8 = (const short8v*)(off + (size_t)i*256 + h*32);
    #pragma unroll
    for (int s=0;s<4;++s){ short8v v = op8[s];
      #pragma unroll
      for (int j=0;j<8;++j) offv[s*8+j] = bf2f((unsigned short)v[j]); }
  }
  float awv[16];
  {
    const short8v* ap8 = (const short8v*)(awl + (size_t)i*128 + h*16);
    #pragma unroll
    for (int s=0;s<2;++s){ short8v v = ap8[s];
      #pragma unroll
      for (int j=0;j<8;++j) awv[s*8+j] = bf2f((unsigned short)v[j]); }
  }
  float m = awv[0];
  #pragma unroll
  for (int k=1;k<16;++k) m = fmaxf(m, awv[k]);
  float sum = 0.f;
  #pragma unroll
  for (int k=0;k<16;++k){ awv[k] = __expf(awv[k]-m); sum += awv[k]; }
  float inv = 1.f/sum;
  #pragma unroll
  for (int k=0;k<16;++k) awv[k] *= inv;

  float acc[16];
  #pragma unroll
  for (int d=0;d<16;++d) acc[d]=0.f;

  #pragma unroll
  for (int lv=0; lv<L_; ++lv){
    const unsigned short* vlv = vmap + ((size_t)b*LQ + lv)*128 + h*16;
    #pragma unroll
    for (int pt=0; pt<NPTS_; ++pt){
      float px = refx + offv[(lv*4+pt)*2+0];
      float py = refy + offv[(lv*4+pt)*2+1];
      float w  = awv[lv*4+pt];
      float fx = floorf(px), fy = floorf(py);
      int x0 = (int)fx, y0 = (int)fy;
      float wx1 = px - fx, wx0 = 1.f - wx1;
      float wy1 = py - fy, wy0 = 1.f - wy1;
      float cw[4] = {w*wy0*wx0, w*wy0*wx1, w*wy1*wx0, w*wy1*wx1};
      int ys[4] = {y0, y0, y0+1, y0+1};
      int xs[4] = {x0, x0+1, x0, x0+1};
      #pragma unroll
      for (int cidx=0; cidx<4; ++cidx){
        int yy = ys[cidx], xx = xs[cidx];
        if (yy>=0 && yy<T_ && xx>=0 && xx<P_){
          const short8v* vp = (const short8v*)(vlv + (size_t)(yy*P_ + xx)*(L_*128));
          short8v v0 = vp[0], v1 = vp[1];
          float wgt = cw[cidx];
          #pragma unroll
          for (int d=0;d<8;++d){
            acc[d]   = fmaf(wgt, bf2f((unsigned short)v0[d]), acc[d]);
            acc[8+d] = fmaf(wgt, bf2f((unsigned short)v1[d]), acc[8+d]);
          }
        }
      }
    }
  }
  short8v o0, o1;
  #pragma unroll
  for (int d=0;d<8;++d){ o0[d] = (short)f2bf(acc[d]); o1[d] = (short)f2bf(acc[8+d]); }
  short8v* op = (short8v*)(o + (size_t)i*C_ + h*DH_);
  op[0] = o0; op[1] = o1;
}

// ---------------- copy level-0 tokens ----------------
__global__ void k_copy_x0(const float* __restrict__ x, float* __restrict__ xcat){
  size_t idx = (size_t)blockIdx.x*blockDim.x + threadIdx.x;
  const size_t n = (size_t)B_*T_*P_*C_;
  if (idx < n){
    size_t c = idx % C_; size_t btp = idx / C_;
    size_t xi = (btp*LL)*C_ + c;
    xcat[xi] = x[xi];
  }
}

// ---------------- MFMA flash attention: wave per (bt, head), builtin-only ----------------
// Swapped QK^T: S^T = K*Q^T via mfma_f32_16x16x32_bf16 with DH=16 zero-padded to K=32
// (lanes g>=2 supply zero fragments). P^T redistributed through per-wave LDS (Pb) so PV
// B-fragments read 8 consecutive keys; PV = 3 MFMAs per q-tile over 96 keys.
// Per-wave LDS (ushorts): Qb[96][20]@0, Kb[96][20]@1920, Vb[16][108]@3840, Pb[16][104]@5568.
#define AT_WAVE 7232
__global__ __launch_bounds__(128) void k_attn3(const unsigned short* __restrict__ qkv,
                                               unsigned short* __restrict__ ca){
  __shared__ unsigned short alds[2*AT_WAVE];
  int w = threadIdx.x >> 6; int lane = threadIdx.x & 63;
  int bt = blockIdx.x >> 2; int hp = blockIdx.x & 3;
  int h = hp*2 + w;
  unsigned short* Qb = alds + w*AT_WAVE;
  unsigned short* Kb = Qb + 1920;
  unsigned short* Vb = Qb + 3840;   // V^T: [d][key], stride 108
  unsigned short* Pb = Qb + 5568;   // P^T as [q][key], stride 104
  // stage: 96 rows x 2 halves (pad rows zeroed)
  for (int idx = lane; idx < 192; idx += 64){
    int s = idx >> 1; int d0 = (idx & 1)*8;
    short8v qv = {}, kv = {}, vv = {};
    if (s < 85){
      const unsigned short* rp = qkv + ((size_t)(bt*85+s))*384 + h*16 + d0;
      qv = *(const short8v*)(rp);
      kv = *(const short8v*)(rp + 128);
      vv = *(const short8v*)(rp + 256);
    }
    *(short8v*)(Qb + s*20 + d0) = qv;
    *(short8v*)(Kb + s*20 + d0) = kv;
    #pragma unroll
    for (int j=0;j<8;++j) Vb[(d0+j)*108 + s] = (unsigned short)vv[j];
  }
  __syncthreads();
  int g = lane >> 4; int li = lane & 15;
  const short8v zero8 = {};
  #pragma unroll 1
  for (int qt = 0; qt < 6; ++qt){
    // B-operand (Q): B[k=dh=g*8+jj][col=q=li]; zero for dh>=16 (g>=2)
    short8v qf = zero8;
    if (g < 2) qf = *(const short8v*)(Qb + (qt*16 + li)*20 + g*8);
    float4v sc[6];
    #pragma unroll
    for (int kt = 0; kt < 6; ++kt){
      // A-operand (K): A[row=key=li][k=dh=g*8+jj]; zero for dh>=16
      short8v kf = zero8;
      if (g < 2) kf = *(const short8v*)(Kb + (kt*16 + li)*20 + g*8);
      float4v z = {};
      sc[kt] = __builtin_amdgcn_mfma_f32_16x16x32_bf16(kf, qf, z, 0, 0, 0);
    }
    // lane (li,g), reg j holds S^T[key = kt*16 + g*4 + j][q = qt*16 + li]
    float m = -1e30f;
    #pragma unroll
    for (int kt = 0; kt < 6; ++kt)
      #pragma unroll
      for (int j = 0; j < 4; ++j){
        float v = sc[kt][j]*0.25f;
        if (kt == 5 && (g*4 + j) >= 5) v = -1e30f;   // keys 85..95 masked
        sc[kt][j] = v;
        m = fmaxf(m, v);
      }
    m = fmaxf(m, __shfl_xor(m, 16));
    m = fmaxf(m, __shfl_xor(m, 32));
    float sum = 0.f;
    #pragma unroll
    for (int kt = 0; kt < 6; ++kt){
      short4v pf;
      #pragma unroll
      for (int j = 0; j < 4; ++j){
        float e = __expf(sc[kt][j] - m);
        sum += e;
        pf[j] = (short)f2bf(e);
      }
      *(short4v*)(Pb + li*104 + kt*16 + g*4) = pf;   // Pb[q=li][key]
    }
    sum += __shfl_xor(sum, 16);
    sum += __shfl_xor(sum, 32);
    float inv = 1.f/sum;
    float4v oacc = {};
    #pragma unroll
    for (int kt32 = 0; kt32 < 3; ++kt32){
      // A (V^T): A[row=d=li][k=key=kt32*32+g*8+jj]; B (P^T): B[k=key][col=q=li]
      short8v vf  = *(const short8v*)(Vb + li*108 + kt32*32 + g*8);
      short8v pf8 = *(const short8v*)(Pb + li*104 + kt32*32 + g*8);
      oacc = __builtin_amdgcn_mfma_f32_16x16x32_bf16(vf, pf8, oacc, 0, 0, 0);
    }
    // lane (li,g), reg j holds O^T[d = g*4 + j][q = qt*16 + li]
    int q = qt*16 + li;
    if (q < 85){
      short4v ov;
      #pragma unroll
      for (int j=0;j<4;++j) ov[j] = (short)f2bf(oacc[j]*inv);
      *(short4v*)(ca + ((size_t)bt*85 + q)*128 + h*16 + g*4) = ov;
    }
  }
}

extern "C" void kernel_launch(void* const* d_in, const int* in_sizes, int n_in,
                              void* d_out, int out_size, void* d_ws, size_t ws_size,
                              hipStream_t stream) {
  (void)in_sizes; (void)n_in; (void)out_size; (void)ws_size;
  const float* x      = (const float*)d_in[0];
  const float* refp   = (const float*)d_in[1];
  const float* pe     = (const float*)d_in[2];
  const float* lpos   = (const float*)d_in[3];
  const float* w_off  = (const float*)d_in[4];
  const float* b_off  = (const float*)d_in[5];
  const float* w_attn = (const float*)d_in[6];
  const float* b_attn = (const float*)d_in[7];
  const float* w_val  = (const float*)d_in[8];
  const float* b_val  = (const float*)d_in[9];
  const float* w_out  = (const float*)d_in[10];
  const float* b_out  = (const float*)d_in[11];
  const float* in_w   = (const float*)d_in[12];
  const float* in_b   = (const float*)d_in[13];
  const float* out_w  = (const float*)d_in[14];
  const float* out_b  = (const float*)d_in[15];
  const float* fc1_w  = (const float*)d_in[16];
  const float* fc1_b  = (const float*)d_in[17];
  const float* fc2_w  = (const float*)d_in[18];
  const float* fc2_b  = (const float*)d_in[19];
  const float* g1     = (const float*)d_in[20];
  const float* be1    = (const float*)d_in[21];
  const float* g2     = (const float*)d_in[22];
  const float* be2    = (const float*)d_in[23];
  const float* g3     = (const float*)d_in[24];
  const float* be3    = (const float*)d_in[25];
  float* out = (float*)d_out;
  char* wsb = (char*)d_ws;

  // ---- workspace layout (byte offsets) ----
  unsigned short* xn_b  = (unsigned short*)(wsb + 0);            // NT1*128 bf16
  unsigned short* q_b   = (unsigned short*)(wsb + 8460288);      // NT1*128 bf16
  unsigned short* off_b = (unsigned short*)(wsb + 16920576);     // NT1*256 bf16
  unsigned short* aw_b  = (unsigned short*)(wsb + 33841152);     // NT1*128 bf16
  unsigned short* vm_b  = (unsigned short*)(wsb + 42301440);     // NT1*128 bf16
  unsigned short* o_b   = (unsigned short*)(wsb + 50761728);     // NT1*128 bf16
  float*          xcatB = (float*)(wsb + 59222016);              // NT2*128 f32
  unsigned short* xn2_b = (unsigned short*)(wsb + 80372736);     // NT2*128 bf16
  unsigned short* qkv_b = (unsigned short*)(wsb + 90948096);     // NT2*384 bf16
  unsigned short* wb    = (unsigned short*)(wsb + 122674176);    // 278528 bf16
  // reuse of dead regions:
  unsigned short* ca_b  = (unsigned short*)(wsb + 0);            // NT2*128 bf16 (xn+q dead)
  unsigned short* ln3_b = (unsigned short*)(wsb + 80372736);     // xn2 dead
  unsigned short* hid_b = (unsigned short*)(wsb + 16920576);     // NT2*512 bf16 (off..o dead)

  unsigned short* wb_off  = wb + 0;
  unsigned short* wb_attn = wb + 32768;
  unsigned short* wb_val  = wb + 49152;
  unsigned short* wb_wout = wb + 65536;
  unsigned short* wb_in   = wb + 81920;
  unsigned short* wb_outw = wb + 131072;
  unsigned short* wb_fc1  = wb + 147456;
  unsigned short* wb_fc2  = wb + 212992;

  const int GM1 = (NT1 + 127)/128;  // 259
  const int GM2 = (NT2 + 127)/128;  // 323

  // 0. weights -> bf16
  hipLaunchKernelGGL(k_wcvt, dim3((278528+255)/256), dim3(256), 0, stream,
                     w_off, w_attn, w_val, w_out, in_w, out_w, fc1_w, fc2_w, wb);
  // 1. LN1 + q
  hipLaunchKernelGGL(k_ln1_q, dim3(NT1/4), dim3(256), 0, stream, x, pe, lpos, g1, be1, xn_b, q_b);
  // 2. off / attn-logits / val  (all bf16 plain outputs)
  hipLaunchKernelGGL((k_mm<128,256,5>), dim3(GM1,2), dim3(256), 0, stream,
                     q_b, wb_off, b_off, nullptr, nullptr, off_b, nullptr, NT1);
  hipLaunchKernelGGL((k_mm<128,128,5>), dim3(GM1,1), dim3(256), 0, stream,
                     q_b, wb_attn, b_attn, nullptr, nullptr, aw_b, nullptr, NT1);
  hipLaunchKernelGGL((k_mm<128,128,5>), dim3(GM1,1), dim3(256), 0, stream,
                     xn_b, wb_val, b_val, nullptr, nullptr, vm_b, nullptr, NT1);
  // 3. fused softmax + deformable sampling
  hipLaunchKernelGGL(k_sample, dim3((NT1*H_+255)/256), dim3(256), 0, stream,
                     off_b, aw_b, refp, vm_b, o_b);
  // 4. out-proj1 + residual -> xcat (levels 1..4), copy level 0
  hipLaunchKernelGGL((k_mm<128,128,2>), dim3(GM1,1), dim3(256), 0, stream,
                     o_b, wb_wout, b_out, nullptr, xcatB, nullptr, x, NT1);
  hipLaunchKernelGGL(k_copy_x0, dim3(((size_t)B_*T_*P_*C_+255)/256), dim3(256), 0, stream, x, xcatB);
  // 5. LN2 -> bf16
  hipLaunchKernelGGL(k_ln, dim3((NT2+3)/4), dim3(256), 0, stream, xcatB, g2, be2, xn2_b, NT2);
  // 6. qkv (bf16)
  hipLaunchKernelGGL((k_mm<128,384,5>), dim3(GM2,3), dim3(256), 0, stream,
                     xn2_b, wb_in, in_b, nullptr, nullptr, qkv_b, nullptr, NT2);
  // 7. MFMA flash attention
  hipLaunchKernelGGL(k_attn3, dim3(B_*T_*4), dim3(128), 0, stream, qkv_b, ca_b);
  // 8. out-proj2 + residual (in-place on xcat)
  hipLaunchKernelGGL((k_mm<128,128,3>), dim3(GM2,1), dim3(256), 0, stream,
                     ca_b, wb_outw, out_b, xcatB, xcatB, nullptr, nullptr, NT2);
  // 9. LN3 -> bf16, FFN, residual
  hipLaunchKernelGGL(k_ln, dim3((NT2+3)/4), dim3(256), 0, stream, xcatB, g3, be3, ln3_b, NT2);
  hipLaunchKernelGGL((k_mm<128,512,4>), dim3(GM2,4), dim3(256), 0, stream,
                     ln3_b, wb_fc1, fc1_b, nullptr, nullptr, hid_b, nullptr, NT2);
  hipLaunchKernelGGL((k_mm<512,128,3>), dim3(GM2,1), dim3(256), 0, stream,
                     hid_b, wb_fc2, fc2_b, xcatB, out, nullptr, nullptr, NT2);
}

// Round 8
// 222.419 us; speedup vs baseline: 8.8300x; 1.1967x over previous
//
#include <hip/hip_runtime.h>
#include <math.h>

#define T_ 243
#define P_ 17
#define L_ 4
#define C_ 128
#define H_ 8
#define NPTS_ 4
#define DH_ 16
#define B_ 2
#define LQ (T_*P_*L_)      /* 16524 */
#define NT1 (B_*LQ)        /* 33048 */
#define LL (L_+1)          /* 5 */
#define S_ (P_*LL)         /* 85 */
#define NT2 (B_*T_*P_*LL)  /* 41310 */

typedef __attribute__((ext_vector_type(8))) short short8v;
typedef __attribute__((ext_vector_type(4))) short short4v;
typedef __attribute__((ext_vector_type(4))) float float4v;

__device__ __forceinline__ unsigned short f2bf(float f){
  union { float f; unsigned u; } un; un.f = f;
  unsigned r = un.u + 0x7FFF + ((un.u >> 16) & 1);   // RNE
  return (unsigned short)(r >> 16);
}
__device__ __forceinline__ float bf2f(unsigned short u){
  union { unsigned u; float f; } un; un.u = ((unsigned)u) << 16; return un.f;
}
// async global->LDS DMA, 16B per lane; dest = wave-uniform base + lane*16 (linear).
// One call covers 4 rows x 16 chunks of a 256B/row tile: row = rb + (lane>>4), chunk = lane&15.
__device__ __forceinline__ void dma16(const unsigned short* g, unsigned short* l){
  __builtin_amdgcn_global_load_lds(
      (const __attribute__((address_space(1))) void*)g,
      (__attribute__((address_space(3))) void*)l, 16, 0, 0);
}

// ---------------- weight convert fp32 -> bf16, layout preserved [N][K] ----------------
__global__ void k_wcvt(const float* __restrict__ w0, const float* __restrict__ w1,
                       const float* __restrict__ w2, const float* __restrict__ w3,
                       const float* __restrict__ w4, const float* __restrict__ w5,
                       const float* __restrict__ w6, const float* __restrict__ w7,
                       unsigned short* __restrict__ dst){
  int i = blockIdx.x*256 + threadIdx.x;
  if (i >= 278528) return;
  float v;
  if      (i < 32768)  v = w0[i];
  else if (i < 49152)  v = w1[i-32768];
  else if (i < 65536)  v = w2[i-49152];
  else if (i < 81920)  v = w3[i-65536];
  else if (i < 131072) v = w4[i-81920];
  else if (i < 147456) v = w5[i-131072];
  else if (i < 212992) v = w6[i-147456];
  else                 v = w7[i-212992];
  dst[i] = f2bf(v);
}

// ---------------- LN1 + q = xn + pe + learn_pos (wave per row) ----------------
__global__ __launch_bounds__(256) void k_ln1_q(
    const float* __restrict__ x, const float* __restrict__ pe,
    const float* __restrict__ lpos, const float* __restrict__ g1,
    const float* __restrict__ be1, unsigned short* __restrict__ xn,
    unsigned short* __restrict__ q) {
  int w = threadIdx.x >> 6; int lane = threadIdx.x & 63;
  int i = blockIdx.x*4 + w;            // NT1 % 4 == 0
  int c = lane*2;
  int b = i / LQ; int r = i % LQ;
  int t = r / (P_*L_); int rp = r % (P_*L_);
  int p = rp / L_; int lv = rp % L_;
  const float* xrow = x + (((size_t)(b*T_+t)*P_ + p)*LL + 1 + lv)*C_;
  float2 v = *(const float2*)(xrow + c);
  float s1 = v.x + v.y, s2 = v.x*v.x + v.y*v.y;
  #pragma unroll
  for (int d=1; d<64; d<<=1){ s1 += __shfl_xor(s1,d); s2 += __shfl_xor(s2,d); }
  float mean = s1*(1.0f/C_);
  float var  = s2*(1.0f/C_) - mean*mean;
  float inv = rsqrtf(var + 1e-5f);
  float2 gg = *(const float2*)(g1 + c);
  float2 bb = *(const float2*)(be1 + c);
  float xn0 = (v.x - mean)*inv*gg.x + bb.x;
  float xn1 = (v.y - mean)*inv*gg.y + bb.y;
  size_t oi = (size_t)i*C_ + c;
  *(unsigned*)(xn + oi) = (unsigned)f2bf(xn0) | ((unsigned)f2bf(xn1) << 16);
  size_t pidx = (((size_t)t*P_ + p)*L_ + lv)*C_ + c;
  float2 pv = *(const float2*)(pe + pidx);
  float2 lp = *(const float2*)(lpos + pidx);
  *(unsigned*)(q + oi) = (unsigned)f2bf(xn0 + pv.x + lp.x) | ((unsigned)f2bf(xn1 + pv.y + lp.y) << 16);
}

// ---------------- generic LN (wave per row, bf16 out) ----------------
__global__ __launch_bounds__(256) void k_ln(
    const float* __restrict__ in, const float* __restrict__ g,
    const float* __restrict__ be, unsigned short* __restrict__ out, int M){
  int w = threadIdx.x >> 6; int lane = threadIdx.x & 63;
  int i = blockIdx.x*4 + w;
  if (i >= M) return;
  int c = lane*2;
  float2 v = *(const float2*)(in + (size_t)i*C_ + c);
  float s1 = v.x + v.y, s2 = v.x*v.x + v.y*v.y;
  #pragma unroll
  for (int d=1; d<64; d<<=1){ s1 += __shfl_xor(s1,d); s2 += __shfl_xor(s2,d); }
  float mean = s1*(1.0f/C_);
  float var  = s2*(1.0f/C_) - mean*mean;
  float inv = rsqrtf(var + 1e-5f);
  float2 gg = *(const float2*)(g + c);
  float2 bb = *(const float2*)(be + c);
  float o0 = (v.x - mean)*inv*gg.x + bb.x;
  float o1 = (v.y - mean)*inv*gg.y + bb.y;
  *(unsigned*)(out + (size_t)i*C_ + c) = (unsigned)f2bf(o0) | ((unsigned)f2bf(o1) << 16);
}

// ---------------- tiled bf16 MFMA GEMM v2 ----------------
// BM=64, BN=128. Row-major LDS tiles with XOR chunk swizzle (pos = chunk ^ (row&7));
// staged via global_load_lds: linear LDS dest + pre-swizzled per-lane SOURCE chunk.
// A: [M][K] bf16, Bw: [N][K] bf16 (original weight layout).
// EPI: 0 fp32  2 OUT1-scatter+res(x)  3 fp32 +res  4 GELU->bf16  5 plain bf16
template<int K, int N, int EPI>
__global__ __launch_bounds__(256) void k_mm(
    const unsigned short* __restrict__ A, const unsigned short* __restrict__ Bw,
    const float* __restrict__ bias, const float* __restrict__ res,
    float* __restrict__ outF, unsigned short* __restrict__ outB,
    const float* __restrict__ xres, int M)
{
  constexpr int NST = K / 128;
  __shared__ unsigned short As[64*128];    // row-major, swizzled chunk positions
  __shared__ unsigned short Bs[128*128];
  int tid = threadIdx.x;
  int lane = tid & 63;
  int w = tid >> 6;
  int lr = lane & 15, kg = lane >> 4;
  int m0 = blockIdx.x * 64;
  int n0 = blockIdx.y * 128;
  int lrow = lane >> 4;                        // 0..3: row within one 4-row DMA
  int lch  = lane & 15;                        // chunk position this lane fills
  float4v acc[8] = {};
  for (int st = 0; st < NST; ++st){
    int kk = st*128;
    if (st) __syncthreads();                   // prev compute done before overwrite
    #pragma unroll
    for (int j = 0; j < 4; ++j){               // A rows: w*16 + j*4 .. +3
      int rb = w*16 + j*4;
      int srcch = lch ^ ((rb + lrow) & 7);
      dma16(A + (size_t)(m0 + rb + lrow)*K + kk + srcch*8, As + rb*128);
    }
    #pragma unroll
    for (int j = 0; j < 8; ++j){               // B rows: w*32 + j*4 .. +3
      int rb = w*32 + j*4;
      int srcch = lch ^ ((rb + lrow) & 7);
      dma16(Bw + (size_t)(n0 + rb + lrow)*K + kk + srcch*8, Bs + rb*128);
    }
    __syncthreads();                           // compiler drains vmcnt before barrier
    #pragma unroll
    for (int ks = 0; ks < 4; ++ks){
      int cn = ks*4 + kg;
      int arow = w*16 + lr;
      short8v af = *(const short8v*)(As + arow*128 + ((cn ^ (arow & 7)) * 8));
      #pragma unroll
      for (int nf = 0; nf < 8; ++nf){
        int brow = nf*16 + lr;
        short8v bf = *(const short8v*)(Bs + brow*128 + ((cn ^ (brow & 7)) * 8));
        acc[nf] = __builtin_amdgcn_mfma_f32_16x16x32_bf16(af, bf, acc[nf], 0, 0, 0);
      }
    }
  }
  // D row = m0 + w*16 + kg*4 + j, col = n0 + nf*16 + lr
  #pragma unroll
  for (int j = 0; j < 4; ++j){
    int gr = m0 + w*16 + kg*4 + j;
    if (gr >= M) continue;
    int b=0,t=0,p=0,lv=0;
    if (EPI == 2){
      b = gr / LQ; int r = gr % LQ;
      t = r / (P_*L_); int rp = r % (P_*L_);
      p = rp / L_; lv = rp % L_;
    }
    #pragma unroll
    for (int nf = 0; nf < 8; ++nf){
      int gc = n0 + nf*16 + lr;
      float v = acc[nf][j] + bias[gc];
      if (EPI == 0) {
        outF[(size_t)gr*N + gc] = v;
      } else if (EPI == 2) {       // out1 scatter into xcat + residual x
        size_t xi = ((((size_t)(b*T_+t)*P_ + p)*LL) + 1 + lv)*(size_t)C_ + gc;
        outF[xi] = v + xres[xi];
      } else if (EPI == 3) {       // += res, fp32 out
        outF[(size_t)gr*N + gc] = v + res[(size_t)gr*N + gc];
      } else if (EPI == 4) {       // GELU -> bf16
        float gv = 0.5f*v*(1.0f + erff(v*0.70710678118654752440f));
        outB[(size_t)gr*N + gc] = f2bf(gv);
      } else if (EPI == 5) {       // plain bf16
        outB[(size_t)gr*N + gc] = f2bf(v);
      }
    }
  }
}

// ---------------- fused softmax + deformable sampling ----------------
__global__ __launch_bounds__(256) void k_sample(
    const unsigned short* __restrict__ off, const unsigned short* __restrict__ awl,
    const float* __restrict__ refp, const unsigned short* __restrict__ vmap,
    unsigned short* __restrict__ o){
  int gid = blockIdx.x*256 + threadIdx.x;
  if (gid >= NT1*H_) return;
  int h = gid & 7; int i = gid >> 3;
  int b = i / LQ; int r = i % LQ;
  int t = r/(P_*L_); int rp = r%(P_*L_); int p = rp/L_;
  size_t rpi = (((size_t)b*T_+t)*P_+p)*2;
  float refx = refp[rpi + 0]*P_ - 0.5f;
  float refy = refp[rpi + 1]*T_ - 0.5f;

  float offv[32];
  {
    const short8v* op8 = (const short8v*)(off + (size_t)i*256 + h*32);
    #pragma unroll
    for (int s=0;s<4;++s){ short8v v = op8[s];
      #pragma unroll
      for (int j=0;j<8;++j) offv[s*8+j] = bf2f((unsigned short)v[j]); }
  }
  float awv[16];
  {
    const short8v* ap8 = (const short8v*)(awl + (size_t)i*128 + h*16);
    #pragma unroll
    for (int s=0;s<2;++s){ short8v v = ap8[s];
      #pragma unroll
      for (int j=0;j<8;++j) awv[s*8+j] = bf2f((unsigned short)v[j]); }
  }
  float m = awv[0];
  #pragma unroll
  for (int k=1;k<16;++k) m = fmaxf(m, awv[k]);
  float sum = 0.f;
  #pragma unroll
  for (int k=0;k<16;++k){ awv[k] = __expf(awv[k]-m); sum += awv[k]; }
  float inv = 1.f/sum;
  #pragma unroll
  for (int k=0;k<16;++k) awv[k] *= inv;

  float acc[16];
  #pragma unroll
  for (int d=0;d<16;++d) acc[d]=0.f;

  #pragma unroll
  for (int lv=0; lv<L_; ++lv){
    const unsigned short* vlv = vmap + ((size_t)b*LQ + lv)*128 + h*16;
    #pragma unroll
    for (int pt=0; pt<NPTS_; ++pt){
      float px = refx + offv[(lv*4+pt)*2+0];
      float py = refy + offv[(lv*4+pt)*2+1];
      float w  = awv[lv*4+pt];
      float fx = floorf(px), fy = floorf(py);
      int x0 = (int)fx, y0 = (int)fy;
      float wx1 = px - fx, wx0 = 1.f - wx1;
      float wy1 = py - fy, wy0 = 1.f - wy1;
      float cw[4] = {w*wy0*wx0, w*wy0*wx1, w*wy1*wx0, w*wy1*wx1};
      int ys[4] = {y0, y0, y0+1, y0+1};
      int xs[4] = {x0, x0+1, x0, x0+1};
      #pragma unroll
      for (int cidx=0; cidx<4; ++cidx){
        int yy = ys[cidx], xx = xs[cidx];
        if (yy>=0 && yy<T_ && xx>=0 && xx<P_){
          const short8v* vp = (const short8v*)(vlv + (size_t)(yy*P_ + xx)*(L_*128));
          short8v v0 = vp[0], v1 = vp[1];
          float wgt = cw[cidx];
          #pragma unroll
          for (int d=0;d<8;++d){
            acc[d]   = fmaf(wgt, bf2f((unsigned short)v0[d]), acc[d]);
            acc[8+d] = fmaf(wgt, bf2f((unsigned short)v1[d]), acc[8+d]);
          }
        }
      }
    }
  }
  short8v o0, o1;
  #pragma unroll
  for (int d=0;d<8;++d){ o0[d] = (short)f2bf(acc[d]); o1[d] = (short)f2bf(acc[8+d]); }
  short8v* op = (short8v*)(o + (size_t)i*C_ + h*DH_);
  op[0] = o0; op[1] = o1;
}

// ---------------- copy level-0 tokens ----------------
__global__ void k_copy_x0(const float* __restrict__ x, float* __restrict__ xcat){
  size_t idx = (size_t)blockIdx.x*blockDim.x + threadIdx.x;
  const size_t n = (size_t)B_*T_*P_*C_;
  if (idx < n){
    size_t c = idx % C_; size_t btp = idx / C_;
    size_t xi = (btp*LL)*C_ + c;
    xcat[xi] = x[xi];
  }
}

// ---------------- MFMA flash attention: wave per (bt, head), builtin-only ----------------
#define AT_WAVE 7232
__global__ __launch_bounds__(128) void k_attn3(const unsigned short* __restrict__ qkv,
                                               unsigned short* __restrict__ ca){
  __shared__ unsigned short alds[2*AT_WAVE];
  int w = threadIdx.x >> 6; int lane = threadIdx.x & 63;
  int bt = blockIdx.x >> 2; int hp = blockIdx.x & 3;
  int h = hp*2 + w;
  unsigned short* Qb = alds + w*AT_WAVE;
  unsigned short* Kb = Qb + 1920;
  unsigned short* Vb = Qb + 3840;   // V^T: [d][key], stride 108
  unsigned short* Pb = Qb + 5568;   // P^T as [q][key], stride 104
  for (int idx = lane; idx < 192; idx += 64){
    int s = idx >> 1; int d0 = (idx & 1)*8;
    short8v qv = {}, kv = {}, vv = {};
    if (s < 85){
      const unsigned short* rp = qkv + ((size_t)(bt*85+s))*384 + h*16 + d0;
      qv = *(const short8v*)(rp);
      kv = *(const short8v*)(rp + 128);
      vv = *(const short8v*)(rp + 256);
    }
    *(short8v*)(Qb + s*20 + d0) = qv;
    *(short8v*)(Kb + s*20 + d0) = kv;
    #pragma unroll
    for (int j=0;j<8;++j) Vb[(d0+j)*108 + s] = (unsigned short)vv[j];
  }
  __syncthreads();
  int g = lane >> 4; int li = lane & 15;
  const short8v zero8 = {};
  #pragma unroll 1
  for (int qt = 0; qt < 6; ++qt){
    short8v qf = zero8;
    if (g < 2) qf = *(const short8v*)(Qb + (qt*16 + li)*20 + g*8);
    float4v sc[6];
    #pragma unroll
    for (int kt = 0; kt < 6; ++kt){
      short8v kf = zero8;
      if (g < 2) kf = *(const short8v*)(Kb + (kt*16 + li)*20 + g*8);
      float4v z = {};
      sc[kt] = __builtin_amdgcn_mfma_f32_16x16x32_bf16(kf, qf, z, 0, 0, 0);
    }
    float m = -1e30f;
    #pragma unroll
    for (int kt = 0; kt < 6; ++kt)
      #pragma unroll
      for (int j = 0; j < 4; ++j){
        float v = sc[kt][j]*0.25f;
        if (kt == 5 && (g*4 + j) >= 5) v = -1e30f;   // keys 85..95 masked
        sc[kt][j] = v;
        m = fmaxf(m, v);
      }
    m = fmaxf(m, __shfl_xor(m, 16));
    m = fmaxf(m, __shfl_xor(m, 32));
    float sum = 0.f;
    #pragma unroll
    for (int kt = 0; kt < 6; ++kt){
      short4v pf;
      #pragma unroll
      for (int j = 0; j < 4; ++j){
        float e = __expf(sc[kt][j] - m);
        sum += e;
        pf[j] = (short)f2bf(e);
      }
      *(short4v*)(Pb + li*104 + kt*16 + g*4) = pf;   // Pb[q=li][key]
    }
    sum += __shfl_xor(sum, 16);
    sum += __shfl_xor(sum, 32);
    float inv = 1.f/sum;
    float4v oacc = {};
    #pragma unroll
    for (int kt32 = 0; kt32 < 3; ++kt32){
      short8v vf  = *(const short8v*)(Vb + li*108 + kt32*32 + g*8);
      short8v pf8 = *(const short8v*)(Pb + li*104 + kt32*32 + g*8);
      oacc = __builtin_amdgcn_mfma_f32_16x16x32_bf16(vf, pf8, oacc, 0, 0, 0);
    }
    int q = qt*16 + li;
    if (q < 85){
      short4v ov;
      #pragma unroll
      for (int j=0;j<4;++j) ov[j] = (short)f2bf(oacc[j]*inv);
      *(short4v*)(ca + ((size_t)bt*85 + q)*128 + h*16 + g*4) = ov;
    }
  }
}

extern "C" void kernel_launch(void* const* d_in, const int* in_sizes, int n_in,
                              void* d_out, int out_size, void* d_ws, size_t ws_size,
                              hipStream_t stream) {
  (void)in_sizes; (void)n_in; (void)out_size; (void)ws_size;
  const float* x      = (const float*)d_in[0];
  const float* refp   = (const float*)d_in[1];
  const float* pe     = (const float*)d_in[2];
  const float* lpos   = (const float*)d_in[3];
  const float* w_off  = (const float*)d_in[4];
  const float* b_off  = (const float*)d_in[5];
  const float* w_attn = (const float*)d_in[6];
  const float* b_attn = (const float*)d_in[7];
  const float* w_val  = (const float*)d_in[8];
  const float* b_val  = (const float*)d_in[9];
  const float* w_out  = (const float*)d_in[10];
  const float* b_out  = (const float*)d_in[11];
  const float* in_w   = (const float*)d_in[12];
  const float* in_b   = (const float*)d_in[13];
  const float* out_w  = (const float*)d_in[14];
  const float* out_b  = (const float*)d_in[15];
  const float* fc1_w  = (const float*)d_in[16];
  const float* fc1_b  = (const float*)d_in[17];
  const float* fc2_w  = (const float*)d_in[18];
  const float* fc2_b  = (const float*)d_in[19];
  const float* g1     = (const float*)d_in[20];
  const float* be1    = (const float*)d_in[21];
  const float* g2     = (const float*)d_in[22];
  const float* be2    = (const float*)d_in[23];
  const float* g3     = (const float*)d_in[24];
  const float* be3    = (const float*)d_in[25];
  float* out = (float*)d_out;
  char* wsb = (char*)d_ws;

  // ---- workspace layout (byte offsets) ----
  unsigned short* xn_b  = (unsigned short*)(wsb + 0);            // NT1*128 bf16
  unsigned short* q_b   = (unsigned short*)(wsb + 8460288);      // NT1*128 bf16
  unsigned short* off_b = (unsigned short*)(wsb + 16920576);     // NT1*256 bf16
  unsigned short* aw_b  = (unsigned short*)(wsb + 33841152);     // NT1*128 bf16
  unsigned short* vm_b  = (unsigned short*)(wsb + 42301440);     // NT1*128 bf16
  unsigned short* o_b   = (unsigned short*)(wsb + 50761728);     // NT1*128 bf16
  float*          xcatB = (float*)(wsb + 59222016);              // NT2*128 f32
  unsigned short* xn2_b = (unsigned short*)(wsb + 80372736);     // NT2*128 bf16
  unsigned short* qkv_b = (unsigned short*)(wsb + 90948096);     // NT2*384 bf16
  unsigned short* wb    = (unsigned short*)(wsb + 122674176);    // 278528 bf16
  // reuse of dead regions:
  unsigned short* ca_b  = (unsigned short*)(wsb + 0);            // NT2*128 bf16 (xn+q dead)
  unsigned short* ln3_b = (unsigned short*)(wsb + 80372736);     // xn2 dead
  unsigned short* hid_b = (unsigned short*)(wsb + 16920576);     // NT2*512 bf16 (off..o dead)

  unsigned short* wb_off  = wb + 0;
  unsigned short* wb_attn = wb + 32768;
  unsigned short* wb_val  = wb + 49152;
  unsigned short* wb_wout = wb + 65536;
  unsigned short* wb_in   = wb + 81920;
  unsigned short* wb_outw = wb + 131072;
  unsigned short* wb_fc1  = wb + 147456;
  unsigned short* wb_fc2  = wb + 212992;

  const int GM1 = (NT1 + 63)/64;  // 517
  const int GM2 = (NT2 + 63)/64;  // 646

  // 0. weights -> bf16
  hipLaunchKernelGGL(k_wcvt, dim3((278528+255)/256), dim3(256), 0, stream,
                     w_off, w_attn, w_val, w_out, in_w, out_w, fc1_w, fc2_w, wb);
  // 1. LN1 + q
  hipLaunchKernelGGL(k_ln1_q, dim3(NT1/4), dim3(256), 0, stream, x, pe, lpos, g1, be1, xn_b, q_b);
  // 2. off / attn-logits / val  (all bf16 plain outputs)
  hipLaunchKernelGGL((k_mm<128,256,5>), dim3(GM1,2), dim3(256), 0, stream,
                     q_b, wb_off, b_off, nullptr, nullptr, off_b, nullptr, NT1);
  hipLaunchKernelGGL((k_mm<128,128,5>), dim3(GM1,1), dim3(256), 0, stream,
                     q_b, wb_attn, b_attn, nullptr, nullptr, aw_b, nullptr, NT1);
  hipLaunchKernelGGL((k_mm<128,128,5>), dim3(GM1,1), dim3(256), 0, stream,
                     xn_b, wb_val, b_val, nullptr, nullptr, vm_b, nullptr, NT1);
  // 3. fused softmax + deformable sampling
  hipLaunchKernelGGL(k_sample, dim3((NT1*H_+255)/256), dim3(256), 0, stream,
                     off_b, aw_b, refp, vm_b, o_b);
  // 4. out-proj1 + residual -> xcat (levels 1..4), copy level 0
  hipLaunchKernelGGL((k_mm<128,128,2>), dim3(GM1,1), dim3(256), 0, stream,
                     o_b, wb_wout, b_out, nullptr, xcatB, nullptr, x, NT1);
  hipLaunchKernelGGL(k_copy_x0, dim3(((size_t)B_*T_*P_*C_+255)/256), dim3(256), 0, stream, x, xcatB);
  // 5. LN2 -> bf16
  hipLaunchKernelGGL(k_ln, dim3((NT2+3)/4), dim3(256), 0, stream, xcatB, g2, be2, xn2_b, NT2);
  // 6. qkv (bf16)
  hipLaunchKernelGGL((k_mm<128,384,5>), dim3(GM2,3), dim3(256), 0, stream,
                     xn2_b, wb_in, in_b, nullptr, nullptr, qkv_b, nullptr, NT2);
  // 7. MFMA flash attention
  hipLaunchKernelGGL(k_attn3, dim3(B_*T_*4), dim3(128), 0, stream, qkv_b, ca_b);
  // 8. out-proj2 + residual (in-place on xcat)
  hipLaunchKernelGGL((k_mm<128,128,3>), dim3(GM2,1), dim3(256), 0, stream,
                     ca_b, wb_outw, out_b, xcatB, xcatB, nullptr, nullptr, NT2);
  // 9. LN3 -> bf16, FFN, residual
  hipLaunchKernelGGL(k_ln, dim3((NT2+3)/4), dim3(256), 0, stream, xcatB, g3, be3, ln3_b, NT2);
  hipLaunchKernelGGL((k_mm<128,512,4>), dim3(GM2,4), dim3(256), 0, stream,
                     ln3_b, wb_fc1, fc1_b, nullptr, nullptr, hid_b, nullptr, NT2);
  hipLaunchKernelGGL((k_mm<512,128,3>), dim3(GM2,1), dim3(256), 0, stream,
                     hid_b, wb_fc2, fc2_b, xcatB, out, nullptr, nullptr, NT2);
}